// Round 10
// baseline (368.634 us; speedup 1.0000x reference)
//
#include <hip/hip_runtime.h>
#include <float.h>
#include <stdint.h>

#define HH 128
#define NROWS 32768
#define KCODES 4096
#define CAPR 40

typedef _Float16 half8 __attribute__((ext_vector_type(8)));
typedef _Float16 half4_t __attribute__((ext_vector_type(4)));
typedef float floatx4 __attribute__((ext_vector_type(4)));
typedef float floatx16 __attribute__((ext_vector_type(16)));

// order-preserving float<->uint key (handles negatives) for LDS atomicMin
__device__ __forceinline__ unsigned fkey(float f) {
    unsigned b = __float_as_uint(f);
    return b ^ ((unsigned)((int)b >> 31) | 0x80000000u);
}
__device__ __forceinline__ float funkey(unsigned k) {
    unsigned b = (k & 0x80000000u) ? (k ^ 0x80000000u) : ~k;
    return __uint_as_float(b);
}

// ---------------------------------------------------------------------------
// ws layout (bytes): 0 wq2R float[4096] (0.5*||w||^2 in MFMA C-register
// order) | 16384 whPart float[256] | 17408 whiA ushort[524288] (1 MB,
// A-frag order) | 1065984 done int[512] (pair handoff counters, 2 KB).
// whiA: chunk (cb = code>>5, s = h/16) = 512 ushorts; entry lane = kh*32 +
// (code&31) holds w_hi[code][s*16 + kh*8 .. +8] (round-0 validated).
// wq2R[cb*32 + kh*16 + r] = 0.5*||w||^2 of code cb*32+(r&3)+8*(r>>2)+4*kh
// (m74/m101 C/D layout).
// Candidate scratch: the pair's OWN out_zq rows (512 B/row, overwritten by
// the final gather): half h uses ints [h*64 .. h*64+63] = {cnt, ovf, codes}.
// ---------------------------------------------------------------------------

__global__ __launch_bounds__(256) void vq_prep(const float* __restrict__ w,
        float* __restrict__ wq2R, ushort* __restrict__ whiA,
        float* __restrict__ whPart, int* __restrict__ done,
        float* __restrict__ loss_slot) {
    __shared__ float sWH[16];
    const int t = threadIdx.x;
    const int tid = blockIdx.x * 256 + t;
    if (tid == 0) loss_slot[0] = 0.0f;   // d_out poisoned 0xAA each launch
    if (tid < 512) done[tid] = 0;        // pair handoff counters
    const int c = tid >> 4, hg = tid & 15, s = hg >> 1, khh = hg & 1;

    const float4* src = reinterpret_cast<const float4*>(w + (size_t)c * HH + (hg << 3));
    float4 a = src[0], b = src[1];
    _Float16 h0=(_Float16)a.x, h1=(_Float16)a.y, h2=(_Float16)a.z, h3=(_Float16)a.w;
    _Float16 h4=(_Float16)b.x, h5=(_Float16)b.y, h6=(_Float16)b.z, h7=(_Float16)b.w;
    half8 hi = {h0, h1, h2, h3, h4, h5, h6, h7};
    *reinterpret_cast<half8*>(&whiA[((size_t)(c >> 5) * 8 + s) * 512 +
                                    (((khh << 5) | (c & 31)) << 3)]) = hi;

    float ssq = 0.f;
    ssq = fmaf(a.x, a.x, ssq); ssq = fmaf(a.y, a.y, ssq);
    ssq = fmaf(a.z, a.z, ssq); ssq = fmaf(a.w, a.w, ssq);
    ssq = fmaf(b.x, b.x, ssq); ssq = fmaf(b.y, b.y, ssq);
    ssq = fmaf(b.z, b.z, ssq); ssq = fmaf(b.w, b.w, ssq);
    ssq += __shfl_xor(ssq, 1, 64);
    ssq += __shfl_xor(ssq, 2, 64);
    ssq += __shfl_xor(ssq, 4, 64);
    ssq += __shfl_xor(ssq, 8, 64);
    if (hg == 0) {
        int co = c & 31;
        wq2R[((c >> 5) << 5) + (((co >> 2) & 1) << 4) + ((co & 3) | ((co >> 3) << 2))]
            = 0.5f * ssq;
        sWH[t >> 4] = ssq;
    }
    __syncthreads();
    if (t == 0) {
        float mh = 0.f;
#pragma unroll
        for (int i = 0; i < 16; ++i) mh = fmaxf(mh, sWH[i]);
        whPart[blockIdx.x] = mh;
    }
}

// ---------------------------------------------------------------------------
// Fused scan, SPLIT-CODEBOOK PAIRS: grid 1024; blocks (2p,2p+1) both own
// rows p*64..+63 but scan disjoint 2048-code halves (16 tiles + re-pass per
// wave = HALF the serial bodies of r9), and 1024 blocks x 4 waves / VGPR<=128
// gives 4 waves/SIMD (2x r9's TLP) at UNCHANGED per-wave ILP -- the one
// untried cell of the TLP x ILP matrix (r8: per-body latency ~const, so
// wall ~ bodies/wave x latency / wave-overlap).
// Rigor: each half collects with bound = own-half min + thrw >= global min
// + thrw => superset of the rigorous window; merged exact eval unchanged.
// Handoff per G16: writer __threadfence + device atomicAdd(done); second
// arriver acquires and runs merged eval + fallback + zq/loss for the pair.
// ---------------------------------------------------------------------------
__global__ __launch_bounds__(256, 2) void vq_fused(
        const float* __restrict__ z, const float* __restrict__ w,
        const float* __restrict__ wq2R, const ushort* __restrict__ whiA,
        const float* __restrict__ whPart, int* __restrict__ done,
        float* __restrict__ out_zq, float* __restrict__ out_idx,
        float* __restrict__ out_loss) {
    __shared__ unsigned smin[64];
    __shared__ int rowcnt[64];
    __shared__ int rowovf[64];
    __shared__ int rowlist[64 * CAPR];
    __shared__ float swh[4];
    __shared__ int fb[64];
    __shared__ float lred[4];
    __shared__ int sIsEval;
    __shared__ __align__(16) float swq[KCODES];   // 16 KB wq2R copy

    const int t = threadIdx.x;
    const int lane = t & 63, wid = t >> 6;
    const int n = lane & 31, kh = lane >> 5;
    const int pairIdx = blockIdx.x >> 1;
    const int half = blockIdx.x & 1;
    const int rowBase = pairIdx * 64;

    // codebook max ||w||^2 partial reduce (256 partials from prep)
    float wp = whPart[t];
#pragma unroll
    for (int off = 1; off < 64; off <<= 1) wp = fmaxf(wp, __shfl_xor(wp, off, 64));
    if (lane == 0) swh[wid] = wp;
    if (t < 64) { smin[t] = 0xFFFFFFFFu; rowcnt[t] = 0; rowovf[t] = 0; }

    // stage wq2R into LDS (epilogue wq2 reads become broadcast ds_reads)
    {
        const float4* g4 = reinterpret_cast<const float4*>(wq2R);
        float4* s4 = reinterpret_cast<float4*>(swq);
#pragma unroll
        for (int i = 0; i < 4; ++i) s4[i * 256 + t] = g4[i * 256 + t];
    }

    // ---- stage z: NEGATED hi fp16 B-frags for rows n and n+32 + norms ----
    half8 zbA[8], zbB[8];
    float zn2A = 0.f, zl2A = 0.f, zn2B = 0.f, zl2B = 0.f;
    {
        const float* zr = z + (size_t)(rowBase + n) * HH + (kh << 3);
#pragma unroll
        for (int s = 0; s < 8; ++s) {
            float4 a = *reinterpret_cast<const float4*>(zr + (s << 4));
            float4 b = *reinterpret_cast<const float4*>(zr + (s << 4) + 4);
            _Float16 h0=(_Float16)a.x, h1=(_Float16)a.y, h2=(_Float16)a.z, h3=(_Float16)a.w;
            _Float16 h4=(_Float16)b.x, h5=(_Float16)b.y, h6=(_Float16)b.z, h7=(_Float16)b.w;
            zbA[s] = (half8){-h0, -h1, -h2, -h3, -h4, -h5, -h6, -h7};
            zn2A = fmaf(a.x,a.x,zn2A); zn2A = fmaf(a.y,a.y,zn2A);
            zn2A = fmaf(a.z,a.z,zn2A); zn2A = fmaf(a.w,a.w,zn2A);
            zn2A = fmaf(b.x,b.x,zn2A); zn2A = fmaf(b.y,b.y,zn2A);
            zn2A = fmaf(b.z,b.z,zn2A); zn2A = fmaf(b.w,b.w,zn2A);
            float l0=a.x-(float)h0, l1=a.y-(float)h1, l2=a.z-(float)h2, l3=a.w-(float)h3;
            float l4=b.x-(float)h4, l5=b.y-(float)h5, l6=b.z-(float)h6, l7=b.w-(float)h7;
            zl2A = fmaf(l0,l0,zl2A); zl2A = fmaf(l1,l1,zl2A);
            zl2A = fmaf(l2,l2,zl2A); zl2A = fmaf(l3,l3,zl2A);
            zl2A = fmaf(l4,l4,zl2A); zl2A = fmaf(l5,l5,zl2A);
            zl2A = fmaf(l6,l6,zl2A); zl2A = fmaf(l7,l7,zl2A);
        }
        const float* zr2 = z + (size_t)(rowBase + 32 + n) * HH + (kh << 3);
#pragma unroll
        for (int s = 0; s < 8; ++s) {
            float4 a = *reinterpret_cast<const float4*>(zr2 + (s << 4));
            float4 b = *reinterpret_cast<const float4*>(zr2 + (s << 4) + 4);
            _Float16 h0=(_Float16)a.x, h1=(_Float16)a.y, h2=(_Float16)a.z, h3=(_Float16)a.w;
            _Float16 h4=(_Float16)b.x, h5=(_Float16)b.y, h6=(_Float16)b.z, h7=(_Float16)b.w;
            zbB[s] = (half8){-h0, -h1, -h2, -h3, -h4, -h5, -h6, -h7};
            zn2B = fmaf(a.x,a.x,zn2B); zn2B = fmaf(a.y,a.y,zn2B);
            zn2B = fmaf(a.z,a.z,zn2B); zn2B = fmaf(a.w,a.w,zn2B);
            zn2B = fmaf(b.x,b.x,zn2B); zn2B = fmaf(b.y,b.y,zn2B);
            zn2B = fmaf(b.z,b.z,zn2B); zn2B = fmaf(b.w,b.w,zn2B);
            float l0=a.x-(float)h0, l1=a.y-(float)h1, l2=a.z-(float)h2, l3=a.w-(float)h3;
            float l4=b.x-(float)h4, l5=b.y-(float)h5, l6=b.z-(float)h6, l7=b.w-(float)h7;
            zl2B = fmaf(l0,l0,zl2B); zl2B = fmaf(l1,l1,zl2B);
            zl2B = fmaf(l2,l2,zl2B); zl2B = fmaf(l3,l3,zl2B);
            zl2B = fmaf(l4,l4,zl2B); zl2B = fmaf(l5,l5,zl2B);
            zl2B = fmaf(l6,l6,zl2B); zl2B = fmaf(l7,l7,zl2B);
        }
        zn2A += __shfl_xor(zn2A, 32, 64);
        zl2A += __shfl_xor(zl2A, 32, 64);
        zn2B += __shfl_xor(zn2B, 32, 64);
        zl2B += __shfl_xor(zl2B, 32, 64);
    }
    __syncthreads();   // smin/cnt init + swh + swq visible

    // rigorous window: |d/2_true - est| <= E; accept if est < runmin + thrw,
    // thrw > 2E => true argmin always collected (half's runmin >= global min
    // => collected set is a SUPERSET of the rigorous window -- still exact).
    float WH = sqrtf(fmaxf(fmaxf(swh[0], swh[1]), fmaxf(swh[2], swh[3])));
    float thrwA, thrwB;
    {
        float znr = sqrtf(zn2A), zlr = sqrtf(zl2A);
        float E = zlr * WH * 1.01f + (znr + zlr) * (WH * 4.8828125e-4f + 1e-6f) + 4e-3f;
        thrwA = 2.0f * E * 1.05f + 0.01f;
        float znr2 = sqrtf(zn2B), zlr2 = sqrtf(zl2B);
        float E2 = zlr2 * WH * 1.01f + (znr2 + zlr2) * (WH * 4.8828125e-4f + 1e-6f) + 4e-3f;
        thrwB = 2.0f * E2 * 1.05f + 0.01f;
    }

    const half8* A8 = reinterpret_cast<const half8*>(whiA);
    const int cb0 = (half << 6) + (wid << 4);   // 16-tile slice of this half
    float m1A = FLT_MAX, m1pA = FLT_MAX, m1B = FLT_MAX, m1pB = FLT_MAX;

    half8 afA[8], afB[8];
    {
        const half8* ap = A8 + ((size_t)cb0 << 3) * 64 + lane;
#pragma unroll
        for (int p = 0; p < 8; ++p) afA[p] = ap[p * 64];
    }

    const floatx16 zac = {0.f,0.f,0.f,0.f,0.f,0.f,0.f,0.f,
                          0.f,0.f,0.f,0.f,0.f,0.f,0.f,0.f};
    floatx16 pend0, pend1;   // pending accs (tile it-1), processed under tile it

    auto proc = [&](int pit, int pcb, const floatx16& wqp, const floatx16& acc,
                    float& m1, float& m1pub, float thrw, int row) {
        float est[16];
#pragma unroll
        for (int r = 0; r < 16; ++r) est[r] = acc[r] + wqp[r];
        float t00=fminf(est[0],est[1]),   t01=fminf(est[2],est[3]);
        float t02=fminf(est[4],est[5]),   t03=fminf(est[6],est[7]);
        float t04=fminf(est[8],est[9]),   t05=fminf(est[10],est[11]);
        float t06=fminf(est[12],est[13]), t07=fminf(est[14],est[15]);
        float tmin = fminf(fminf(fminf(t00,t01), fminf(t02,t03)),
                           fminf(fminf(t04,t05), fminf(t06,t07)));
        m1 = fminf(m1, tmin);
        if (m1 < m1pub) { atomicMin(&smin[row], fkey(m1)); m1pub = m1; }
        if (pit > 0 && tmin < m1 + thrw) {
            float sh = funkey(((volatile unsigned*)smin)[row]);
            float bound = fminf(sh, m1) + thrw;
            if (tmin < bound) {
                unsigned cm = 0;
#pragma unroll
                for (int r = 0; r < 16; ++r)
                    if (est[r] < bound) cm |= (1u << r);
                int cc = __popc(cm);
                int ix = atomicAdd(&rowcnt[row], cc);
                if (ix + cc > CAPR) rowovf[row] = 1;
#pragma unroll
                for (int r = 0; r < 16; ++r) {
                    if (cm & (1u << r)) {
                        if (ix < CAPR)
                            rowlist[row * CAPR + ix] =
                                (pcb << 5) + (r & 3) + ((r >> 2) << 3) + (kh << 2);
                        ++ix;
                    }
                }
            }
        }
    };

    auto procPair = [&](int pit) {
        const int pcb = cb0 + ((pit < 16) ? pit : 0);
        const floatx16 wqp =
            *reinterpret_cast<const floatx16*>(&swq[(pcb << 5) + (kh << 4)]);
        proc(pit, pcb, wqp, pend0, m1A, m1pA, thrwA, n);
        proc(pit, pcb, wqp, pend1, m1B, m1pB, thrwB, n + 32);
    };

    auto body = [&](int it, half8 (&cur)[8], half8 (&nxt)[8]) {
        if (it < 16) {
            const int cbn = cb0 + ((it + 1) & 15);
            const half8* ap = A8 + ((size_t)cbn << 3) * 64 + lane;
#pragma unroll
            for (int p = 0; p < 8; ++p) nxt[p] = ap[p * 64];
        }
        floatx16 a0 = __builtin_amdgcn_mfma_f32_32x32x16_f16(cur[0], zbA[0], zac, 0, 0, 0);
        floatx16 a1 = __builtin_amdgcn_mfma_f32_32x32x16_f16(cur[0], zbB[0], zac, 0, 0, 0);
#pragma unroll
        for (int s = 1; s < 8; ++s) {
            a0 = __builtin_amdgcn_mfma_f32_32x32x16_f16(cur[s], zbA[s], a0, 0, 0, 0);
            a1 = __builtin_amdgcn_mfma_f32_32x32x16_f16(cur[s], zbB[s], a1, 0, 0, 0);
        }
        if (it > 0) procPair(it - 1);
        pend0 = a0; pend1 = a1;
    };

#pragma unroll 1
    for (int itp = 0; itp < 8; ++itp) {
        body(2 * itp,     afA, afB);
        body(2 * itp + 1, afB, afA);
    }
    body(16, afA, afB);   // re-pass tile 0 (warm bound)
    procPair(16);         // drain last pending (tile 0, collect=true)
    __syncthreads();

    // ---- publish candidates to the pair's out_zq scratch (half region) ----
    if (t < 64) {
        int cnt = rowcnt[t];
        int ccp = cnt > CAPR ? CAPR : cnt;
        int* gs = reinterpret_cast<int*>(out_zq + (size_t)(rowBase + t) * HH)
                  + (half << 6);
        gs[0] = ccp;
        gs[1] = rowovf[t];
        for (int j = 0; j < ccp; ++j) gs[2 + j] = rowlist[t * CAPR + j];
    }
    __threadfence();   // device-scope release (cross-XCD, G16)
    __syncthreads();
    if (t == 0) sIsEval = (atomicAdd(&done[pairIdx], 1) == 1) ? 1 : 0;
    __syncthreads();
    if (!sIsEval) return;       // first arriver: peer will do the merge
    __threadfence();            // acquire: invalidate stale L2 before reads

    // ---- merged exact fp32 eval (4 threads per row, both halves) ----
    {
        const int erow = t >> 2, eq = t & 3;
        const int* gsA = reinterpret_cast<const int*>(
                             out_zq + (size_t)(rowBase + erow) * HH);
        const int* gsB = gsA + 64;
        int cA = gsA[0], oA = gsA[1], cB = gsB[0], oB = gsB[1];
        int cnt = cA + cB;
        bool ovf = (oA != 0) || (oB != 0) || (cnt == 0);
        if (eq == 0) rowovf[erow] = ovf ? 1 : 0;
        if (!ovf) {
            const float* zs = z + (size_t)(rowBase + erow) * HH + (eq << 5);
            float4 z0 = *reinterpret_cast<const float4*>(zs);
            float4 z1 = *reinterpret_cast<const float4*>(zs + 4);
            float4 z2 = *reinterpret_cast<const float4*>(zs + 8);
            float4 z3 = *reinterpret_cast<const float4*>(zs + 12);
            float4 z4v = *reinterpret_cast<const float4*>(zs + 16);
            float4 z5 = *reinterpret_cast<const float4*>(zs + 20);
            float4 z6 = *reinterpret_cast<const float4*>(zs + 24);
            float4 z7 = *reinterpret_cast<const float4*>(zs + 28);
            float bd = FLT_MAX; int bc = 0x7fffffff;
            for (int j = 0; j < cnt; ++j) {
                int c = (j < cA) ? gsA[2 + j] : gsB[2 + j - cA];
                const float* wr = w + (size_t)c * HH + (eq << 5);
                float4 w0 = *reinterpret_cast<const float4*>(wr);
                float4 w1 = *reinterpret_cast<const float4*>(wr + 4);
                float4 w2 = *reinterpret_cast<const float4*>(wr + 8);
                float4 w3 = *reinterpret_cast<const float4*>(wr + 12);
                float4 w4 = *reinterpret_cast<const float4*>(wr + 16);
                float4 w5 = *reinterpret_cast<const float4*>(wr + 20);
                float4 w6 = *reinterpret_cast<const float4*>(wr + 24);
                float4 w7 = *reinterpret_cast<const float4*>(wr + 28);
                float dot = 0.f;
                dot = fmaf(z0.x,w0.x,dot); dot = fmaf(z0.y,w0.y,dot);
                dot = fmaf(z0.z,w0.z,dot); dot = fmaf(z0.w,w0.w,dot);
                dot = fmaf(z1.x,w1.x,dot); dot = fmaf(z1.y,w1.y,dot);
                dot = fmaf(z1.z,w1.z,dot); dot = fmaf(z1.w,w1.w,dot);
                dot = fmaf(z2.x,w2.x,dot); dot = fmaf(z2.y,w2.y,dot);
                dot = fmaf(z2.z,w2.z,dot); dot = fmaf(z2.w,w2.w,dot);
                dot = fmaf(z3.x,w3.x,dot); dot = fmaf(z3.y,w3.y,dot);
                dot = fmaf(z3.z,w3.z,dot); dot = fmaf(z3.w,w3.w,dot);
                dot = fmaf(z4v.x,w4.x,dot); dot = fmaf(z4v.y,w4.y,dot);
                dot = fmaf(z4v.z,w4.z,dot); dot = fmaf(z4v.w,w4.w,dot);
                dot = fmaf(z5.x,w5.x,dot); dot = fmaf(z5.y,w5.y,dot);
                dot = fmaf(z5.z,w5.z,dot); dot = fmaf(z5.w,w5.w,dot);
                dot = fmaf(z6.x,w6.x,dot); dot = fmaf(z6.y,w6.y,dot);
                dot = fmaf(z6.z,w6.z,dot); dot = fmaf(z6.w,w6.w,dot);
                dot = fmaf(z7.x,w7.x,dot); dot = fmaf(z7.y,w7.y,dot);
                dot = fmaf(z7.z,w7.z,dot); dot = fmaf(z7.w,w7.w,dot);
                dot += __shfl_xor(dot, 1, 64);
                dot += __shfl_xor(dot, 2, 64);
                int co = c & 31;
                float wq2v = swq[((c >> 5) << 5) + (((co >> 2) & 1) << 4)
                                 + ((co & 3) | ((co >> 3) << 2))];
                float d2 = wq2v - dot;
                if (d2 < bd || (d2 == bd && c < bc)) { bd = d2; bc = c; }
            }
            if (eq == 0) { fb[erow] = bc; out_idx[rowBase + erow] = (float)bc; }
        }
    }
    __syncthreads();

    // ---- rigorous fallback: full exact scan for overflow rows (~never) ----
    for (int rr = wid; rr < 64; rr += 4) {
        if (rowovf[rr] == 0) continue;
        const float* zrow = z + (size_t)(rowBase + rr) * HH;
        float bd = FLT_MAX; int bc = 0x7fffffff;
        for (int kq = 0; kq < 64; ++kq) {
            int c = (kq << 6) + lane;
            const float* wr = w + (size_t)c * HH;
            float dot = 0.f;
            for (int h4 = 0; h4 < 32; ++h4) {
                float4 wv = *reinterpret_cast<const float4*>(wr + (h4 << 2));
                float4 zv = *reinterpret_cast<const float4*>(zrow + (h4 << 2));
                dot = fmaf(zv.x,wv.x,dot); dot = fmaf(zv.y,wv.y,dot);
                dot = fmaf(zv.z,wv.z,dot); dot = fmaf(zv.w,wv.w,dot);
            }
            int co = c & 31;
            float wq2v = swq[((c >> 5) << 5) + (((co >> 2) & 1) << 4)
                             + ((co & 3) | ((co >> 3) << 2))];
            float d2 = wq2v - dot;
            if (d2 < bd || (d2 == bd && c < bc)) { bd = d2; bc = c; }
        }
#pragma unroll
        for (int off = 1; off < 64; off <<= 1) {
            float od = __shfl_xor(bd, off, 64);
            int oc = __shfl_xor(bc, off, 64);
            if (od < bd || (od == bd && oc < bc)) { bd = od; bc = oc; }
        }
        if (lane == 0) { fb[rr] = bc; out_idx[rowBase + rr] = (float)bc; }
    }
    __syncthreads();

    // ---- zq gather + loss (overwrites the cand scratch -- after eval) ----
    const float4* z4 = reinterpret_cast<const float4*>(z);
    float lsum = 0.f;
#pragma unroll
    for (int i = 0; i < 8; ++i) {
        int g = i * 256 + t;
        int r = g >> 5, f4 = g & 31;
        int code = fb[r];
        float4 wv = *reinterpret_cast<const float4*>(w + (size_t)code * HH + (f4 << 2));
        float4 zv = z4[(size_t)(rowBase + r) * 32 + f4];
        float dx = wv.x - zv.x, dy = wv.y - zv.y, dz = wv.z - zv.z, dw = wv.w - zv.w;
        lsum = fmaf(dx, dx, lsum); lsum = fmaf(dy, dy, lsum);
        lsum = fmaf(dz, dz, lsum); lsum = fmaf(dw, dw, lsum);
        *reinterpret_cast<float4*>(out_zq + (size_t)(rowBase + r) * HH + (f4 << 2)) = wv;
    }
#pragma unroll
    for (int off = 1; off < 64; off <<= 1) lsum += __shfl_xor(lsum, off, 64);
    if (lane == 0) lred[wid] = lsum;
    __syncthreads();
    if (t == 0) {
        float total = lred[0] + lred[1] + lred[2] + lred[3];
        atomicAdd(out_loss, total * (1.25f / 4194304.0f));  // (0.25+1)*mean, N*H
    }
}

// ---------------- fallback path (Round-2 kernels, proven) -------------------
__device__ __forceinline__ int plane_off_fb(int r, int hu) {
    return ((hu << 6) | (r ^ (hu & 7))) << 3;
}

__global__ __launch_bounds__(256) void vq_prep_fb(const float* __restrict__ w,
                                                  float* __restrict__ wsq,
                                                  float* __restrict__ loss_slot) {
    int c = blockIdx.x * 256 + threadIdx.x;
    if (c == 0) loss_slot[0] = 0.0f;
    if (c < KCODES) {
        const float4* row = reinterpret_cast<const float4*>(w + (size_t)c * HH);
        float s = 0.0f;
#pragma unroll
        for (int i = 0; i < HH / 4; ++i) {
            float4 v = row[i];
            s = fmaf(v.x, v.x, s); s = fmaf(v.y, v.y, s);
            s = fmaf(v.z, v.z, s); s = fmaf(v.w, v.w, s);
        }
        wsq[c] = s;
    }
}

__device__ __forceinline__ void stage_tile_fb(const float4* __restrict__ src4,
                                              ushort* lds, int hi_base, int lo_base,
                                              int t) {
#pragma unroll
    for (int p = 0; p < 8; ++p) {
        int g = p * 256 + t;
        int r = g >> 5, f4 = g & 31;
        float4 v = src4[g];
        _Float16 h0 = (_Float16)v.x, h1 = (_Float16)v.y,
                 h2 = (_Float16)v.z, h3 = (_Float16)v.w;
        half4_t hv = {h0, h1, h2, h3};
        half4_t lv = {(_Float16)(v.x - (float)h0), (_Float16)(v.y - (float)h1),
                      (_Float16)(v.z - (float)h2), (_Float16)(v.w - (float)h3)};
        int off = plane_off_fb(r, f4 >> 1) + ((f4 & 1) << 2);
        *reinterpret_cast<half4_t*>(&lds[hi_base + off]) = hv;
        *reinterpret_cast<half4_t*>(&lds[lo_base + off]) = lv;
    }
}

__global__ __launch_bounds__(256, 2) void vq_main_fb(const float* __restrict__ z,
                                                     const float* __restrict__ w,
                                                     const float* __restrict__ wsq,
                                                     float* __restrict__ out_zq,
                                                     float* __restrict__ out_idx,
                                                     float* __restrict__ out_loss) {
    __shared__ __align__(16) ushort lds[32768];
    const int t = threadIdx.x, lane = t & 63, wid = t >> 6;
    const int q = lane >> 4, m15 = lane & 15;
    const int wrow = (wid >> 1) << 5, wcol = (wid & 1) << 5;
    const int rowBase = blockIdx.x * 64;

    stage_tile_fb(reinterpret_cast<const float4*>(z + (size_t)rowBase * HH), lds, 0, 8192, t);

    float best[2][4]; int bidx[2][4];
#pragma unroll
    for (int mt = 0; mt < 2; ++mt)
#pragma unroll
        for (int rg = 0; rg < 4; ++rg) { best[mt][rg] = FLT_MAX; bidx[mt][rg] = 0; }

    const int ar0 = wrow + m15, bn0 = wcol + m15;

    for (int k0 = 0; k0 < KCODES; k0 += 64) {
        __syncthreads();
        stage_tile_fb(reinterpret_cast<const float4*>(w + (size_t)k0 * HH), lds, 16384, 24576, t);
        __syncthreads();
        floatx4 acc[2][2];
#pragma unroll
        for (int mt = 0; mt < 2; ++mt)
#pragma unroll
            for (int nt = 0; nt < 2; ++nt) acc[mt][nt] = (floatx4){0.f, 0.f, 0.f, 0.f};
#pragma unroll
        for (int c = 0; c < 4; ++c) {
            const int hu = (c << 2) + q;
            half8 zh0 = *reinterpret_cast<half8*>(&lds[plane_off_fb(ar0, hu)]);
            half8 zh1 = *reinterpret_cast<half8*>(&lds[plane_off_fb(ar0 + 16, hu)]);
            half8 zl0 = *reinterpret_cast<half8*>(&lds[8192 + plane_off_fb(ar0, hu)]);
            half8 zl1 = *reinterpret_cast<half8*>(&lds[8192 + plane_off_fb(ar0 + 16, hu)]);
            half8 wh0 = *reinterpret_cast<half8*>(&lds[16384 + plane_off_fb(bn0, hu)]);
            half8 wh1 = *reinterpret_cast<half8*>(&lds[16384 + plane_off_fb(bn0 + 16, hu)]);
            half8 wl0 = *reinterpret_cast<half8*>(&lds[24576 + plane_off_fb(bn0, hu)]);
            half8 wl1 = *reinterpret_cast<half8*>(&lds[24576 + plane_off_fb(bn0 + 16, hu)]);
            acc[0][0] = __builtin_amdgcn_mfma_f32_16x16x32_f16(zh0, wh0, acc[0][0], 0, 0, 0);
            acc[0][1] = __builtin_amdgcn_mfma_f32_16x16x32_f16(zh0, wh1, acc[0][1], 0, 0, 0);
            acc[1][0] = __builtin_amdgcn_mfma_f32_16x16x32_f16(zh1, wh0, acc[1][0], 0, 0, 0);
            acc[1][1] = __builtin_amdgcn_mfma_f32_16x16x32_f16(zh1, wh1, acc[1][1], 0, 0, 0);
            acc[0][0] = __builtin_amdgcn_mfma_f32_16x16x32_f16(zh0, wl0, acc[0][0], 0, 0, 0);
            acc[0][1] = __builtin_amdgcn_mfma_f32_16x16x32_f16(zh0, wl1, acc[0][1], 0, 0, 0);
            acc[1][0] = __builtin_amdgcn_mfma_f32_16x16x32_f16(zh1, wl0, acc[1][0], 0, 0, 0);
            acc[1][1] = __builtin_amdgcn_mfma_f32_16x16x32_f16(zh1, wl1, acc[1][1], 0, 0, 0);
            acc[0][0] = __builtin_amdgcn_mfma_f32_16x16x32_f16(zl0, wh0, acc[0][0], 0, 0, 0);
            acc[0][1] = __builtin_amdgcn_mfma_f32_16x16x32_f16(zl0, wh1, acc[0][1], 0, 0, 0);
            acc[1][0] = __builtin_amdgcn_mfma_f32_16x16x32_f16(zl1, wh0, acc[1][0], 0, 0, 0);
            acc[1][1] = __builtin_amdgcn_mfma_f32_16x16x32_f16(zl1, wh1, acc[1][1], 0, 0, 0);
        }
        float wq0 = wsq[k0 + bn0], wq1 = wsq[k0 + bn0 + 16];
#pragma unroll
        for (int mt = 0; mt < 2; ++mt)
#pragma unroll
            for (int nt = 0; nt < 2; ++nt) {
                int code = k0 + wcol + (nt << 4) + m15;
                float wqv = nt ? wq1 : wq0;
#pragma unroll
                for (int rg = 0; rg < 4; ++rg) {
                    float s = fmaf(-2.0f, acc[mt][nt][rg], wqv);
                    if (s < best[mt][rg]) { best[mt][rg] = s; bidx[mt][rg] = code; }
                }
            }
    }
#pragma unroll
    for (int off = 1; off < 16; off <<= 1)
#pragma unroll
        for (int mt = 0; mt < 2; ++mt)
#pragma unroll
            for (int rg = 0; rg < 4; ++rg) {
                float os = __shfl_xor(best[mt][rg], off, 64);
                int   oi = __shfl_xor(bidx[mt][rg], off, 64);
                if (os < best[mt][rg] || (os == best[mt][rg] && oi < bidx[mt][rg])) {
                    best[mt][rg] = os; bidx[mt][rg] = oi;
                }
            }
    float* epmin = reinterpret_cast<float*>(lds);
    int*   epidx = reinterpret_cast<int*>(reinterpret_cast<char*>(lds) + 512);
    int*   fbidx = reinterpret_cast<int*>(reinterpret_cast<char*>(lds) + 1024);
    float* lredf = reinterpret_cast<float*>(reinterpret_cast<char*>(lds) + 1280);
    __syncthreads();
    if (m15 == 0) {
        int g = wid & 1;
#pragma unroll
        for (int mt = 0; mt < 2; ++mt)
#pragma unroll
            for (int rg = 0; rg < 4; ++rg) {
                int row = wrow + (mt << 4) + (q << 2) + rg;
                epmin[g * 64 + row] = best[mt][rg];
                epidx[g * 64 + row] = bidx[mt][rg];
            }
    }
    __syncthreads();
    if (t < 64) {
        float s0 = epmin[t], s1 = epmin[64 + t];
        int   i0 = epidx[t], i1 = epidx[64 + t];
        int   fi = (s1 < s0 || (s1 == s0 && i1 < i0)) ? i1 : i0;
        fbidx[t] = fi;
        out_idx[rowBase + t] = (float)fi;
    }
    __syncthreads();
    const float4* z4 = reinterpret_cast<const float4*>(z);
    float lsum = 0.0f;
#pragma unroll
    for (int i = 0; i < 8; ++i) {
        int g = i * 256 + t;
        int r = g >> 5, f4 = g & 31;
        int code = fbidx[r];
        float4 wv = *reinterpret_cast<const float4*>(w + (size_t)code * HH + (f4 << 2));
        float4 zv = z4[(size_t)(rowBase + r) * 32 + f4];
        float dx = wv.x - zv.x, dy = wv.y - zv.y, dz = wv.z - zv.z, dw = wv.w - zv.w;
        lsum = fmaf(dx, dx, lsum); lsum = fmaf(dy, dy, lsum);
        lsum = fmaf(dz, dz, lsum); lsum = fmaf(dw, dw, lsum);
        *reinterpret_cast<float4*>(out_zq + (size_t)(rowBase + r) * HH + (f4 << 2)) = wv;
    }
#pragma unroll
    for (int off = 1; off < 64; off <<= 1) lsum += __shfl_xor(lsum, off, 64);
    if (lane == 0) lredf[wid] = lsum;
    __syncthreads();
    if (t == 0)
        atomicAdd(out_loss, (lredf[0] + lredf[1] + lredf[2] + lredf[3]) * (1.25f / 4194304.0f));
}

extern "C" void kernel_launch(void* const* d_in, const int* in_sizes, int n_in,
                              void* d_out, int out_size, void* d_ws, size_t ws_size,
                              hipStream_t stream) {
    (void)in_sizes; (void)n_in; (void)out_size;
    const float* z = (const float*)d_in[0];
    const float* w = (const float*)d_in[1];
    float* out      = (float*)d_out;
    float* out_zq   = out;
    float* out_idx  = out + (size_t)NROWS * HH;
    float* out_loss = out_idx + NROWS;

    char* wsb = (char*)d_ws;
    float*  wq2R   = (float*)(wsb + 0);          // 16 KB
    float*  whPart = (float*)(wsb + 16384);      // 1 KB
    ushort* whiA   = (ushort*)(wsb + 17408);     // 1 MB f16 codes, A-frag order
    int*    done   = (int*)(wsb + 17408 + (size_t)KCODES * HH * 2);  // 2 KB
    const size_t WS_NEED = 17408 + (size_t)KCODES * HH * 2 + 2048;

    if (ws_size >= WS_NEED) {
        vq_prep<<<256, 256, 0, stream>>>(w, wq2R, whiA, whPart, done, out_loss);
        vq_fused<<<NROWS / 32, 256, 0, stream>>>(z, w, wq2R, whiA, whPart, done,
                                                 out_zq, out_idx, out_loss);
    } else {
        float* wsq = (float*)d_ws;
        vq_prep_fb<<<KCODES / 256, 256, 0, stream>>>(w, wsq, out_loss);
        vq_main_fb<<<NROWS / 64, 256, 0, stream>>>(z, w, wsq, out_zq, out_idx, out_loss);
    }
}

// Round 11
// 163.688 us; speedup vs baseline: 2.2521x; 2.2521x over previous
//
#include <hip/hip_runtime.h>
#include <float.h>
#include <stdint.h>

#define HH 128
#define NROWS 32768
#define KCODES 4096
#define CAPR 40

typedef _Float16 half8 __attribute__((ext_vector_type(8)));
typedef _Float16 half4_t __attribute__((ext_vector_type(4)));
typedef float floatx4 __attribute__((ext_vector_type(4)));
typedef float floatx16 __attribute__((ext_vector_type(16)));

// order-preserving float<->uint key (handles negatives) for LDS atomicMin
__device__ __forceinline__ unsigned fkey(float f) {
    unsigned b = __float_as_uint(f);
    return b ^ ((unsigned)((int)b >> 31) | 0x80000000u);
}
__device__ __forceinline__ float funkey(unsigned k) {
    unsigned b = (k & 0x80000000u) ? (k ^ 0x80000000u) : ~k;
    return __uint_as_float(b);
}

// ---------------------------------------------------------------------------
// ws layout (bytes): 0 wq2R float[4096] (0.5*||w||^2 in MFMA C-register
// order) | 16384 whPart float[256] | 17408 whiA ushort[524288] (1 MB,
// A-frag order). whiA: chunk (cb = code>>5, s = h/16) = 512 ushorts; entry
// lane = kh*32 + (code&31) holds w_hi[code][s*16 + kh*8 .. +8] (round-0
// validated). wq2R[cb*32 + kh*16 + r] = 0.5*||w||^2 of code
// cb*32+(r&3)+8*(r>>2)+4*kh (m74/m101 C/D layout).
// ---------------------------------------------------------------------------

__global__ __launch_bounds__(256) void vq_prep(const float* __restrict__ w,
        float* __restrict__ wq2R, ushort* __restrict__ whiA,
        float* __restrict__ whPart, float* __restrict__ loss_slot) {
    __shared__ float sWH[16];
    const int t = threadIdx.x;
    const int tid = blockIdx.x * 256 + t;
    if (tid == 0) loss_slot[0] = 0.0f;   // d_out poisoned 0xAA each launch
    const int c = tid >> 4, hg = tid & 15, s = hg >> 1, khh = hg & 1;

    const float4* src = reinterpret_cast<const float4*>(w + (size_t)c * HH + (hg << 3));
    float4 a = src[0], b = src[1];
    _Float16 h0=(_Float16)a.x, h1=(_Float16)a.y, h2=(_Float16)a.z, h3=(_Float16)a.w;
    _Float16 h4=(_Float16)b.x, h5=(_Float16)b.y, h6=(_Float16)b.z, h7=(_Float16)b.w;
    half8 hi = {h0, h1, h2, h3, h4, h5, h6, h7};
    *reinterpret_cast<half8*>(&whiA[((size_t)(c >> 5) * 8 + s) * 512 +
                                    (((khh << 5) | (c & 31)) << 3)]) = hi;

    float ssq = 0.f;
    ssq = fmaf(a.x, a.x, ssq); ssq = fmaf(a.y, a.y, ssq);
    ssq = fmaf(a.z, a.z, ssq); ssq = fmaf(a.w, a.w, ssq);
    ssq = fmaf(b.x, b.x, ssq); ssq = fmaf(b.y, b.y, ssq);
    ssq = fmaf(b.z, b.z, ssq); ssq = fmaf(b.w, b.w, ssq);
    ssq += __shfl_xor(ssq, 1, 64);
    ssq += __shfl_xor(ssq, 2, 64);
    ssq += __shfl_xor(ssq, 4, 64);
    ssq += __shfl_xor(ssq, 8, 64);
    if (hg == 0) {
        int co = c & 31;
        wq2R[((c >> 5) << 5) + (((co >> 2) & 1) << 4) + ((co & 3) | ((co >> 3) << 2))]
            = 0.5f * ssq;
        sWH[t >> 4] = ssq;
    }
    __syncthreads();
    if (t == 0) {
        float mh = 0.f;
#pragma unroll
        for (int i = 0; i < 16; ++i) mh = fmaxf(mh, sWH[i]);
        whPart[blockIdx.x] = mh;
    }
}

// ---------------------------------------------------------------------------
// Fused scan (r9 base: 64 rows/block, 4 waves, grid 512, pipelined epilogue)
// + PREFETCH DEPTH 2: triple-buffered A-fragments, loads for body i issued
// at body i-2 (~2 bodies of compute to cover L2-under-load latency).
// Rationale: r6 vs r9 showed chains/procs hide under a per-body FIXED cost
// (the depth-1 prefetch wait); r10's cross-block split is disqualified
// (threadfence L2 invalidation destroyed the cache-resident codebook).
// ---------------------------------------------------------------------------
__global__ __launch_bounds__(256, 2) void vq_fused(
        const float* __restrict__ z, const float* __restrict__ w,
        const float* __restrict__ wq2R, const ushort* __restrict__ whiA,
        const float* __restrict__ whPart,
        float* __restrict__ out_zq, float* __restrict__ out_idx,
        float* __restrict__ out_loss) {
    __shared__ unsigned smin[64];
    __shared__ int rowcnt[64];
    __shared__ int rowovf[64];
    __shared__ int rowlist[64 * CAPR];
    __shared__ float swh[4];
    __shared__ int fb[64];
    __shared__ float lred[4];
    __shared__ __align__(16) float swq[KCODES];   // 16 KB wq2R copy

    const int t = threadIdx.x;
    const int lane = t & 63, wid = t >> 6;
    const int n = lane & 31, kh = lane >> 5;
    const int rowBase = blockIdx.x * 64;

    // codebook max ||w||^2 partial reduce (256 partials from prep)
    float wp = whPart[t];
#pragma unroll
    for (int off = 1; off < 64; off <<= 1) wp = fmaxf(wp, __shfl_xor(wp, off, 64));
    if (lane == 0) swh[wid] = wp;
    if (t < 64) { smin[t] = 0xFFFFFFFFu; rowcnt[t] = 0; rowovf[t] = 0; }

    // stage wq2R into LDS (epilogue wq2 reads become broadcast ds_reads)
    {
        const float4* g4 = reinterpret_cast<const float4*>(wq2R);
        float4* s4 = reinterpret_cast<float4*>(swq);
#pragma unroll
        for (int i = 0; i < 4; ++i) s4[i * 256 + t] = g4[i * 256 + t];
    }

    // ---- stage z: NEGATED hi fp16 B-frags for rows n and n+32 + norms ----
    half8 zbA[8], zbB[8];
    float zn2A = 0.f, zl2A = 0.f, zn2B = 0.f, zl2B = 0.f;
    {
        const float* zr = z + (size_t)(rowBase + n) * HH + (kh << 3);
#pragma unroll
        for (int s = 0; s < 8; ++s) {
            float4 a = *reinterpret_cast<const float4*>(zr + (s << 4));
            float4 b = *reinterpret_cast<const float4*>(zr + (s << 4) + 4);
            _Float16 h0=(_Float16)a.x, h1=(_Float16)a.y, h2=(_Float16)a.z, h3=(_Float16)a.w;
            _Float16 h4=(_Float16)b.x, h5=(_Float16)b.y, h6=(_Float16)b.z, h7=(_Float16)b.w;
            zbA[s] = (half8){-h0, -h1, -h2, -h3, -h4, -h5, -h6, -h7};
            zn2A = fmaf(a.x,a.x,zn2A); zn2A = fmaf(a.y,a.y,zn2A);
            zn2A = fmaf(a.z,a.z,zn2A); zn2A = fmaf(a.w,a.w,zn2A);
            zn2A = fmaf(b.x,b.x,zn2A); zn2A = fmaf(b.y,b.y,zn2A);
            zn2A = fmaf(b.z,b.z,zn2A); zn2A = fmaf(b.w,b.w,zn2A);
            float l0=a.x-(float)h0, l1=a.y-(float)h1, l2=a.z-(float)h2, l3=a.w-(float)h3;
            float l4=b.x-(float)h4, l5=b.y-(float)h5, l6=b.z-(float)h6, l7=b.w-(float)h7;
            zl2A = fmaf(l0,l0,zl2A); zl2A = fmaf(l1,l1,zl2A);
            zl2A = fmaf(l2,l2,zl2A); zl2A = fmaf(l3,l3,zl2A);
            zl2A = fmaf(l4,l4,zl2A); zl2A = fmaf(l5,l5,zl2A);
            zl2A = fmaf(l6,l6,zl2A); zl2A = fmaf(l7,l7,zl2A);
        }
        const float* zr2 = z + (size_t)(rowBase + 32 + n) * HH + (kh << 3);
#pragma unroll
        for (int s = 0; s < 8; ++s) {
            float4 a = *reinterpret_cast<const float4*>(zr2 + (s << 4));
            float4 b = *reinterpret_cast<const float4*>(zr2 + (s << 4) + 4);
            _Float16 h0=(_Float16)a.x, h1=(_Float16)a.y, h2=(_Float16)a.z, h3=(_Float16)a.w;
            _Float16 h4=(_Float16)b.x, h5=(_Float16)b.y, h6=(_Float16)b.z, h7=(_Float16)b.w;
            zbB[s] = (half8){-h0, -h1, -h2, -h3, -h4, -h5, -h6, -h7};
            zn2B = fmaf(a.x,a.x,zn2B); zn2B = fmaf(a.y,a.y,zn2B);
            zn2B = fmaf(a.z,a.z,zn2B); zn2B = fmaf(a.w,a.w,zn2B);
            zn2B = fmaf(b.x,b.x,zn2B); zn2B = fmaf(b.y,b.y,zn2B);
            zn2B = fmaf(b.z,b.z,zn2B); zn2B = fmaf(b.w,b.w,zn2B);
            float l0=a.x-(float)h0, l1=a.y-(float)h1, l2=a.z-(float)h2, l3=a.w-(float)h3;
            float l4=b.x-(float)h4, l5=b.y-(float)h5, l6=b.z-(float)h6, l7=b.w-(float)h7;
            zl2B = fmaf(l0,l0,zl2B); zl2B = fmaf(l1,l1,zl2B);
            zl2B = fmaf(l2,l2,zl2B); zl2B = fmaf(l3,l3,zl2B);
            zl2B = fmaf(l4,l4,zl2B); zl2B = fmaf(l5,l5,zl2B);
            zl2B = fmaf(l6,l6,zl2B); zl2B = fmaf(l7,l7,zl2B);
        }
        zn2A += __shfl_xor(zn2A, 32, 64);
        zl2A += __shfl_xor(zl2A, 32, 64);
        zn2B += __shfl_xor(zn2B, 32, 64);
        zl2B += __shfl_xor(zl2B, 32, 64);
    }
    __syncthreads();   // smin/cnt init + swh + swq visible

    // rigorous window: |d/2_true - est| <= E; accept if est < runmin + thrw,
    // thrw > 2E  =>  true argmin always collected; non-collected strictly
    // worse. (late wq2-add ulps covered by the 1.01x / +4e-3 slack terms,
    // and guarded by the exact re-eval.)
    float WH = sqrtf(fmaxf(fmaxf(swh[0], swh[1]), fmaxf(swh[2], swh[3])));
    float thrwA, thrwB;
    {
        float znr = sqrtf(zn2A), zlr = sqrtf(zl2A);
        float E = zlr * WH * 1.01f + (znr + zlr) * (WH * 4.8828125e-4f + 1e-6f) + 4e-3f;
        thrwA = 2.0f * E * 1.05f + 0.01f;
        float znr2 = sqrtf(zn2B), zlr2 = sqrtf(zl2B);
        float E2 = zlr2 * WH * 1.01f + (znr2 + zlr2) * (WH * 4.8828125e-4f + 1e-6f) + 4e-3f;
        thrwB = 2.0f * E2 * 1.05f + 0.01f;
    }

    const half8* A8 = reinterpret_cast<const half8*>(whiA);
    const int cb0 = wid << 5;
    float m1A = FLT_MAX, m1pA = FLT_MAX, m1B = FLT_MAX, m1pB = FLT_MAX;

    // triple-buffered A-fragments: body it consumes buf[it%3]; loads for
    // body it+2 are issued during body it (depth-2 prefetch).
    half8 afA[8], afB[8], afC[8];
    {
        const half8* ap0 = A8 + ((size_t)cb0 << 3) * 64 + lane;            // tile 0
        const half8* ap1 = A8 + ((size_t)(cb0 + 1) << 3) * 64 + lane;      // tile 1
#pragma unroll
        for (int p = 0; p < 8; ++p) afA[p] = ap0[p * 64];
#pragma unroll
        for (int p = 0; p < 8; ++p) afB[p] = ap1[p * 64];
    }

    const floatx16 zac = {0.f,0.f,0.f,0.f,0.f,0.f,0.f,0.f,
                          0.f,0.f,0.f,0.f,0.f,0.f,0.f,0.f};
    floatx16 pend0, pend1;   // pending accs (tile it-1), processed under tile it

    auto proc = [&](int pit, int pcb, const floatx16& wqp, const floatx16& acc,
                    float& m1, float& m1pub, float thrw, int row) {
        float est[16];
#pragma unroll
        for (int r = 0; r < 16; ++r) est[r] = acc[r] + wqp[r];
        float t00=fminf(est[0],est[1]),   t01=fminf(est[2],est[3]);
        float t02=fminf(est[4],est[5]),   t03=fminf(est[6],est[7]);
        float t04=fminf(est[8],est[9]),   t05=fminf(est[10],est[11]);
        float t06=fminf(est[12],est[13]), t07=fminf(est[14],est[15]);
        float tmin = fminf(fminf(fminf(t00,t01), fminf(t02,t03)),
                           fminf(fminf(t04,t05), fminf(t06,t07)));
        m1 = fminf(m1, tmin);
        if (m1 < m1pub) { atomicMin(&smin[row], fkey(m1)); m1pub = m1; }
        // register-only pre-check: shared bound <= local bound, so a local
        // fail proves no candidate here (m1 already includes this tile)
        if (pit > 0 && tmin < m1 + thrw) {
            float sh = funkey(((volatile unsigned*)smin)[row]);
            float bound = fminf(sh, m1) + thrw;
            if (tmin < bound) {
                unsigned cm = 0;
#pragma unroll
                for (int r = 0; r < 16; ++r)
                    if (est[r] < bound) cm |= (1u << r);
                int cc = __popc(cm);
                int ix = atomicAdd(&rowcnt[row], cc);
                if (ix + cc > CAPR) rowovf[row] = 1;
#pragma unroll
                for (int r = 0; r < 16; ++r) {
                    if (cm & (1u << r)) {
                        if (ix < CAPR)
                            rowlist[row * CAPR + ix] =
                                (pcb << 5) + (r & 3) + ((r >> 2) << 3) + (kh << 2);
                        ++ix;
                    }
                }
            }
        }
    };

    auto procPair = [&](int pit) {
        const int pcb = cb0 + ((pit < 32) ? pit : 0);
        const floatx16 wqp =
            *reinterpret_cast<const floatx16*>(&swq[(pcb << 5) + (kh << 4)]);
        proc(pit, pcb, wqp, pend0, m1A, m1pA, thrwA, n);
        proc(pit, pcb, wqp, pend1, m1B, m1pB, thrwB, n + 32);
    };

    // body(it, cur, pf): consume cur (tile it, or tile 0 for the it==32
    // re-pass); prefetch tile for body it+2 into pf (skip when it+2 > 32).
    auto body = [&](int it, half8 (&cur)[8], half8 (&pf)[8]) {
        const int tgt = it + 2;
        if (tgt <= 32) {
            const int cbn = cb0 + ((tgt < 32) ? tgt : 0);
            const half8* ap = A8 + ((size_t)cbn << 3) * 64 + lane;
#pragma unroll
            for (int p = 0; p < 8; ++p) pf[p] = ap[p * 64];
        }
        // zero-C chains: no ds_read on the critical path; wq2 added in proc
        floatx16 a0 = __builtin_amdgcn_mfma_f32_32x32x16_f16(cur[0], zbA[0], zac, 0, 0, 0);
        floatx16 a1 = __builtin_amdgcn_mfma_f32_32x32x16_f16(cur[0], zbB[0], zac, 0, 0, 0);
#pragma unroll
        for (int s = 1; s < 8; ++s) {
            a0 = __builtin_amdgcn_mfma_f32_32x32x16_f16(cur[s], zbA[s], a0, 0, 0, 0);
            a1 = __builtin_amdgcn_mfma_f32_32x32x16_f16(cur[s], zbB[s], a1, 0, 0, 0);
        }
        // process PREVIOUS tile's accs while this tile's MFMAs are in flight
        if (it > 0) procPair(it - 1);
        pend0 = a0; pend1 = a1;
    };

    // 33 bodies (it = 0..32; it==32 re-passes tile 0 with warm bound),
    // 3-phase buffer rotation, all indices compile-time static (rule #20).
#pragma unroll 1
    for (int itp = 0; itp < 11; ++itp) {
        body(3 * itp,     afA, afC);
        body(3 * itp + 1, afB, afA);
        body(3 * itp + 2, afC, afB);
    }
    procPair(32);         // drain the last pending (tile 0, collect=true)
    __syncthreads();

    // ---- exact fp32 eval of candidates (4 threads per row, 64 rows) ----
    {
        const int erow = t >> 2, eq = t & 3;
        int cnt = rowcnt[erow];
        bool ovf = (rowovf[erow] != 0) || (cnt > CAPR) || (cnt == 0);
        if (cnt > CAPR) cnt = CAPR;
        if (ovf) {
            if (eq == 0) rowovf[erow] = 1;
        } else {
            const float* zs = z + (size_t)(rowBase + erow) * HH + (eq << 5);
            float4 z0 = *reinterpret_cast<const float4*>(zs);
            float4 z1 = *reinterpret_cast<const float4*>(zs + 4);
            float4 z2 = *reinterpret_cast<const float4*>(zs + 8);
            float4 z3 = *reinterpret_cast<const float4*>(zs + 12);
            float4 z4v = *reinterpret_cast<const float4*>(zs + 16);
            float4 z5 = *reinterpret_cast<const float4*>(zs + 20);
            float4 z6 = *reinterpret_cast<const float4*>(zs + 24);
            float4 z7 = *reinterpret_cast<const float4*>(zs + 28);
            float bd = FLT_MAX; int bc = 0x7fffffff;
            for (int j = 0; j < cnt; ++j) {
                int c = rowlist[erow * CAPR + j];
                const float* wr = w + (size_t)c * HH + (eq << 5);
                float4 w0 = *reinterpret_cast<const float4*>(wr);
                float4 w1 = *reinterpret_cast<const float4*>(wr + 4);
                float4 w2 = *reinterpret_cast<const float4*>(wr + 8);
                float4 w3 = *reinterpret_cast<const float4*>(wr + 12);
                float4 w4 = *reinterpret_cast<const float4*>(wr + 16);
                float4 w5 = *reinterpret_cast<const float4*>(wr + 20);
                float4 w6 = *reinterpret_cast<const float4*>(wr + 24);
                float4 w7 = *reinterpret_cast<const float4*>(wr + 28);
                float dot = 0.f;
                dot = fmaf(z0.x,w0.x,dot); dot = fmaf(z0.y,w0.y,dot);
                dot = fmaf(z0.z,w0.z,dot); dot = fmaf(z0.w,w0.w,dot);
                dot = fmaf(z1.x,w1.x,dot); dot = fmaf(z1.y,w1.y,dot);
                dot = fmaf(z1.z,w1.z,dot); dot = fmaf(z1.w,w1.w,dot);
                dot = fmaf(z2.x,w2.x,dot); dot = fmaf(z2.y,w2.y,dot);
                dot = fmaf(z2.z,w2.z,dot); dot = fmaf(z2.w,w2.w,dot);
                dot = fmaf(z3.x,w3.x,dot); dot = fmaf(z3.y,w3.y,dot);
                dot = fmaf(z3.z,w3.z,dot); dot = fmaf(z3.w,w3.w,dot);
                dot = fmaf(z4v.x,w4.x,dot); dot = fmaf(z4v.y,w4.y,dot);
                dot = fmaf(z4v.z,w4.z,dot); dot = fmaf(z4v.w,w4.w,dot);
                dot = fmaf(z5.x,w5.x,dot); dot = fmaf(z5.y,w5.y,dot);
                dot = fmaf(z5.z,w5.z,dot); dot = fmaf(z5.w,w5.w,dot);
                dot = fmaf(z6.x,w6.x,dot); dot = fmaf(z6.y,w6.y,dot);
                dot = fmaf(z6.z,w6.z,dot); dot = fmaf(z6.w,w6.w,dot);
                dot = fmaf(z7.x,w7.x,dot); dot = fmaf(z7.y,w7.y,dot);
                dot = fmaf(z7.z,w7.z,dot); dot = fmaf(z7.w,w7.w,dot);
                dot += __shfl_xor(dot, 1, 64);
                dot += __shfl_xor(dot, 2, 64);
                int co = c & 31;
                float wq2v = swq[((c >> 5) << 5) + (((co >> 2) & 1) << 4)
                                 + ((co & 3) | ((co >> 3) << 2))];
                float d2 = wq2v - dot;
                if (d2 < bd || (d2 == bd && c < bc)) { bd = d2; bc = c; }
            }
            if (eq == 0) { fb[erow] = bc; out_idx[rowBase + erow] = (float)bc; }
        }
    }
    __syncthreads();

    // ---- rigorous fallback: full exact scan for overflow rows (~never),
    // rows distributed across the 4 waves ----
    for (int rr = wid; rr < 64; rr += 4) {
        if (rowovf[rr] == 0) continue;
        const float* zrow = z + (size_t)(rowBase + rr) * HH;
        float bd = FLT_MAX; int bc = 0x7fffffff;
        for (int kq = 0; kq < 64; ++kq) {
            int c = (kq << 6) + lane;
            const float* wr = w + (size_t)c * HH;
            float dot = 0.f;
            for (int h4 = 0; h4 < 32; ++h4) {
                float4 wv = *reinterpret_cast<const float4*>(wr + (h4 << 2));
                float4 zv = *reinterpret_cast<const float4*>(zrow + (h4 << 2));
                dot = fmaf(zv.x,wv.x,dot); dot = fmaf(zv.y,wv.y,dot);
                dot = fmaf(zv.z,wv.z,dot); dot = fmaf(zv.w,wv.w,dot);
            }
            int co = c & 31;
            float wq2v = swq[((c >> 5) << 5) + (((co >> 2) & 1) << 4)
                             + ((co & 3) | ((co >> 3) << 2))];
            float d2 = wq2v - dot;
            if (d2 < bd || (d2 == bd && c < bc)) { bd = d2; bc = c; }
        }
#pragma unroll
        for (int off = 1; off < 64; off <<= 1) {
            float od = __shfl_xor(bd, off, 64);
            int oc = __shfl_xor(bc, off, 64);
            if (od < bd || (od == bd && oc < bc)) { bd = od; bc = oc; }
        }
        if (lane == 0) { fb[rr] = bc; out_idx[rowBase + rr] = (float)bc; }
    }
    __syncthreads();

    // ---- zq gather + loss (proven epilogue) ----
    const float4* z4 = reinterpret_cast<const float4*>(z);
    float lsum = 0.f;
#pragma unroll
    for (int i = 0; i < 8; ++i) {
        int g = i * 256 + t;
        int r = g >> 5, f4 = g & 31;
        int code = fb[r];
        float4 wv = *reinterpret_cast<const float4*>(w + (size_t)code * HH + (f4 << 2));
        float4 zv = z4[(size_t)(rowBase + r) * 32 + f4];
        float dx = wv.x - zv.x, dy = wv.y - zv.y, dz = wv.z - zv.z, dw = wv.w - zv.w;
        lsum = fmaf(dx, dx, lsum); lsum = fmaf(dy, dy, lsum);
        lsum = fmaf(dz, dz, lsum); lsum = fmaf(dw, dw, lsum);
        *reinterpret_cast<float4*>(out_zq + (size_t)(rowBase + r) * HH + (f4 << 2)) = wv;
    }
#pragma unroll
    for (int off = 1; off < 64; off <<= 1) lsum += __shfl_xor(lsum, off, 64);
    if (lane == 0) lred[wid] = lsum;
    __syncthreads();
    if (t == 0) {
        float total = lred[0] + lred[1] + lred[2] + lred[3];
        atomicAdd(out_loss, total * (1.25f / 4194304.0f));  // (0.25+1)*mean, N*H
    }
}

// ---------------- fallback path (Round-2 kernels, proven) -------------------
__device__ __forceinline__ int plane_off_fb(int r, int hu) {
    return ((hu << 6) | (r ^ (hu & 7))) << 3;
}

__global__ __launch_bounds__(256) void vq_prep_fb(const float* __restrict__ w,
                                                  float* __restrict__ wsq,
                                                  float* __restrict__ loss_slot) {
    int c = blockIdx.x * 256 + threadIdx.x;
    if (c == 0) loss_slot[0] = 0.0f;
    if (c < KCODES) {
        const float4* row = reinterpret_cast<const float4*>(w + (size_t)c * HH);
        float s = 0.0f;
#pragma unroll
        for (int i = 0; i < HH / 4; ++i) {
            float4 v = row[i];
            s = fmaf(v.x, v.x, s); s = fmaf(v.y, v.y, s);
            s = fmaf(v.z, v.z, s); s = fmaf(v.w, v.w, s);
        }
        wsq[c] = s;
    }
}

__device__ __forceinline__ void stage_tile_fb(const float4* __restrict__ src4,
                                              ushort* lds, int hi_base, int lo_base,
                                              int t) {
#pragma unroll
    for (int p = 0; p < 8; ++p) {
        int g = p * 256 + t;
        int r = g >> 5, f4 = g & 31;
        float4 v = src4[g];
        _Float16 h0 = (_Float16)v.x, h1 = (_Float16)v.y,
                 h2 = (_Float16)v.z, h3 = (_Float16)v.w;
        half4_t hv = {h0, h1, h2, h3};
        half4_t lv = {(_Float16)(v.x - (float)h0), (_Float16)(v.y - (float)h1),
                      (_Float16)(v.z - (float)h2), (_Float16)(v.w - (float)h3)};
        int off = plane_off_fb(r, f4 >> 1) + ((f4 & 1) << 2);
        *reinterpret_cast<half4_t*>(&lds[hi_base + off]) = hv;
        *reinterpret_cast<half4_t*>(&lds[lo_base + off]) = lv;
    }
}

__global__ __launch_bounds__(256, 2) void vq_main_fb(const float* __restrict__ z,
                                                     const float* __restrict__ w,
                                                     const float* __restrict__ wsq,
                                                     float* __restrict__ out_zq,
                                                     float* __restrict__ out_idx,
                                                     float* __restrict__ out_loss) {
    __shared__ __align__(16) ushort lds[32768];
    const int t = threadIdx.x, lane = t & 63, wid = t >> 6;
    const int q = lane >> 4, m15 = lane & 15;
    const int wrow = (wid >> 1) << 5, wcol = (wid & 1) << 5;
    const int rowBase = blockIdx.x * 64;

    stage_tile_fb(reinterpret_cast<const float4*>(z + (size_t)rowBase * HH), lds, 0, 8192, t);

    float best[2][4]; int bidx[2][4];
#pragma unroll
    for (int mt = 0; mt < 2; ++mt)
#pragma unroll
        for (int rg = 0; rg < 4; ++rg) { best[mt][rg] = FLT_MAX; bidx[mt][rg] = 0; }

    const int ar0 = wrow + m15, bn0 = wcol + m15;

    for (int k0 = 0; k0 < KCODES; k0 += 64) {
        __syncthreads();
        stage_tile_fb(reinterpret_cast<const float4*>(w + (size_t)k0 * HH), lds, 16384, 24576, t);
        __syncthreads();
        floatx4 acc[2][2];
#pragma unroll
        for (int mt = 0; mt < 2; ++mt)
#pragma unroll
            for (int nt = 0; nt < 2; ++nt) acc[mt][nt] = (floatx4){0.f, 0.f, 0.f, 0.f};
#pragma unroll
        for (int c = 0; c < 4; ++c) {
            const int hu = (c << 2) + q;
            half8 zh0 = *reinterpret_cast<half8*>(&lds[plane_off_fb(ar0, hu)]);
            half8 zh1 = *reinterpret_cast<half8*>(&lds[plane_off_fb(ar0 + 16, hu)]);
            half8 zl0 = *reinterpret_cast<half8*>(&lds[8192 + plane_off_fb(ar0, hu)]);
            half8 zl1 = *reinterpret_cast<half8*>(&lds[8192 + plane_off_fb(ar0 + 16, hu)]);
            half8 wh0 = *reinterpret_cast<half8*>(&lds[16384 + plane_off_fb(bn0, hu)]);
            half8 wh1 = *reinterpret_cast<half8*>(&lds[16384 + plane_off_fb(bn0 + 16, hu)]);
            half8 wl0 = *reinterpret_cast<half8*>(&lds[24576 + plane_off_fb(bn0, hu)]);
            half8 wl1 = *reinterpret_cast<half8*>(&lds[24576 + plane_off_fb(bn0 + 16, hu)]);
            acc[0][0] = __builtin_amdgcn_mfma_f32_16x16x32_f16(zh0, wh0, acc[0][0], 0, 0, 0);
            acc[0][1] = __builtin_amdgcn_mfma_f32_16x16x32_f16(zh0, wh1, acc[0][1], 0, 0, 0);
            acc[1][0] = __builtin_amdgcn_mfma_f32_16x16x32_f16(zh1, wh0, acc[1][0], 0, 0, 0);
            acc[1][1] = __builtin_amdgcn_mfma_f32_16x16x32_f16(zh1, wh1, acc[1][1], 0, 0, 0);
            acc[0][0] = __builtin_amdgcn_mfma_f32_16x16x32_f16(zh0, wl0, acc[0][0], 0, 0, 0);
            acc[0][1] = __builtin_amdgcn_mfma_f32_16x16x32_f16(zh0, wl1, acc[0][1], 0, 0, 0);
            acc[1][0] = __builtin_amdgcn_mfma_f32_16x16x32_f16(zh1, wl0, acc[1][0], 0, 0, 0);
            acc[1][1] = __builtin_amdgcn_mfma_f32_16x16x32_f16(zh1, wl1, acc[1][1], 0, 0, 0);
            acc[0][0] = __builtin_amdgcn_mfma_f32_16x16x32_f16(zl0, wh0, acc[0][0], 0, 0, 0);
            acc[0][1] = __builtin_amdgcn_mfma_f32_16x16x32_f16(zl0, wh1, acc[0][1], 0, 0, 0);
            acc[1][0] = __builtin_amdgcn_mfma_f32_16x16x32_f16(zl1, wh0, acc[1][0], 0, 0, 0);
            acc[1][1] = __builtin_amdgcn_mfma_f32_16x16x32_f16(zl1, wh1, acc[1][1], 0, 0, 0);
        }
        float wq0 = wsq[k0 + bn0], wq1 = wsq[k0 + bn0 + 16];
#pragma unroll
        for (int mt = 0; mt < 2; ++mt)
#pragma unroll
            for (int nt = 0; nt < 2; ++nt) {
                int code = k0 + wcol + (nt << 4) + m15;
                float wqv = nt ? wq1 : wq0;
#pragma unroll
                for (int rg = 0; rg < 4; ++rg) {
                    float s = fmaf(-2.0f, acc[mt][nt][rg], wqv);
                    if (s < best[mt][rg]) { best[mt][rg] = s; bidx[mt][rg] = code; }
                }
            }
    }
#pragma unroll
    for (int off = 1; off < 16; off <<= 1)
#pragma unroll
        for (int mt = 0; mt < 2; ++mt)
#pragma unroll
            for (int rg = 0; rg < 4; ++rg) {
                float os = __shfl_xor(best[mt][rg], off, 64);
                int   oi = __shfl_xor(bidx[mt][rg], off, 64);
                if (os < best[mt][rg] || (os == best[mt][rg] && oi < bidx[mt][rg])) {
                    best[mt][rg] = os; bidx[mt][rg] = oi;
                }
            }
    float* epmin = reinterpret_cast<float*>(lds);
    int*   epidx = reinterpret_cast<int*>(reinterpret_cast<char*>(lds) + 512);
    int*   fbidx = reinterpret_cast<int*>(reinterpret_cast<char*>(lds) + 1024);
    float* lredf = reinterpret_cast<float*>(reinterpret_cast<char*>(lds) + 1280);
    __syncthreads();
    if (m15 == 0) {
        int g = wid & 1;
#pragma unroll
        for (int mt = 0; mt < 2; ++mt)
#pragma unroll
            for (int rg = 0; rg < 4; ++rg) {
                int row = wrow + (mt << 4) + (q << 2) + rg;
                epmin[g * 64 + row] = best[mt][rg];
                epidx[g * 64 + row] = bidx[mt][rg];
            }
    }
    __syncthreads();
    if (t < 64) {
        float s0 = epmin[t], s1 = epmin[64 + t];
        int   i0 = epidx[t], i1 = epidx[64 + t];
        int   fi = (s1 < s0 || (s1 == s0 && i1 < i0)) ? i1 : i0;
        fbidx[t] = fi;
        out_idx[rowBase + t] = (float)fi;
    }
    __syncthreads();
    const float4* z4 = reinterpret_cast<const float4*>(z);
    float lsum = 0.0f;
#pragma unroll
    for (int i = 0; i < 8; ++i) {
        int g = i * 256 + t;
        int r = g >> 5, f4 = g & 31;
        int code = fbidx[r];
        float4 wv = *reinterpret_cast<const float4*>(w + (size_t)code * HH + (f4 << 2));
        float4 zv = z4[(size_t)(rowBase + r) * 32 + f4];
        float dx = wv.x - zv.x, dy = wv.y - zv.y, dz = wv.z - zv.z, dw = wv.w - zv.w;
        lsum = fmaf(dx, dx, lsum); lsum = fmaf(dy, dy, lsum);
        lsum = fmaf(dz, dz, lsum); lsum = fmaf(dw, dw, lsum);
        *reinterpret_cast<float4*>(out_zq + (size_t)(rowBase + r) * HH + (f4 << 2)) = wv;
    }
#pragma unroll
    for (int off = 1; off < 64; off <<= 1) lsum += __shfl_xor(lsum, off, 64);
    if (lane == 0) lredf[wid] = lsum;
    __syncthreads();
    if (t == 0)
        atomicAdd(out_loss, (lredf[0] + lredf[1] + lredf[2] + lredf[3]) * (1.25f / 4194304.0f));
}

extern "C" void kernel_launch(void* const* d_in, const int* in_sizes, int n_in,
                              void* d_out, int out_size, void* d_ws, size_t ws_size,
                              hipStream_t stream) {
    (void)in_sizes; (void)n_in; (void)out_size;
    const float* z = (const float*)d_in[0];
    const float* w = (const float*)d_in[1];
    float* out      = (float*)d_out;
    float* out_zq   = out;
    float* out_idx  = out + (size_t)NROWS * HH;
    float* out_loss = out_idx + NROWS;

    char* wsb = (char*)d_ws;
    float*  wq2R   = (float*)(wsb + 0);        // 16 KB
    float*  whPart = (float*)(wsb + 16384);    // 1 KB
    ushort* whiA   = (ushort*)(wsb + 17408);   // 1 MB f16 codes, A-frag order
    const size_t WS_NEED = 17408 + (size_t)KCODES * HH * 2;

    if (ws_size >= WS_NEED) {
        vq_prep<<<256, 256, 0, stream>>>(w, wq2R, whiA, whPart, out_loss);
        vq_fused<<<NROWS / 64, 256, 0, stream>>>(z, w, wq2R, whiA, whPart,
                                                 out_zq, out_idx, out_loss);
    } else {
        float* wsq = (float*)d_ws;
        vq_prep_fb<<<KCODES / 256, 256, 0, stream>>>(w, wsq, out_loss);
        vq_main_fb<<<NROWS / 64, 256, 0, stream>>>(z, w, wsq, out_zq, out_idx, out_loss);
    }
}

// Round 12
// 133.114 us; speedup vs baseline: 2.7693x; 1.2297x over previous
//
#include <hip/hip_runtime.h>
#include <float.h>
#include <stdint.h>

#define HH 128
#define NROWS 32768
#define KCODES 4096
#define CAPR 40

typedef _Float16 half8 __attribute__((ext_vector_type(8)));
typedef _Float16 half4_t __attribute__((ext_vector_type(4)));
typedef float floatx4 __attribute__((ext_vector_type(4)));
typedef float floatx16 __attribute__((ext_vector_type(16)));

// order-preserving float<->uint key (handles negatives) for LDS atomicMin
__device__ __forceinline__ unsigned fkey(float f) {
    unsigned b = __float_as_uint(f);
    return b ^ ((unsigned)((int)b >> 31) | 0x80000000u);
}
__device__ __forceinline__ float funkey(unsigned k) {
    unsigned b = (k & 0x80000000u) ? (k ^ 0x80000000u) : ~k;
    return __uint_as_float(b);
}

// ---------------------------------------------------------------------------
// ws layout (bytes): 0 wq2R float[4096] (0.5*||w||^2 in MFMA C-register
// order) | 16384 whPart float[256] | 17408 whiA ushort[524288] (1 MB,
// A-frag order). whiA: chunk (cb = code>>5, s = h/16) = 512 ushorts; entry
// lane = kh*32 + (code&31) holds w_hi[code][s*16 + kh*8 .. +8] (round-0
// validated). wq2R[cb*32 + kh*16 + r] = 0.5*||w||^2 of code
// cb*32+(r&3)+8*(r>>2)+4*kh (m74/m101 C/D layout).
//
// SESSION LEDGER (why this exact structure): r3/r9 = 75-76 us fused is the
// plateau. Refuted: wider blocks (r4/r5: spill), TLP-for-ILP swap (r6: +10),
// LDS A-sharing w/ barriers (r7: +25), 1-wave extreme ILP (r8: +52),
// cross-block split w/ threadfence (r10: +283, L2 invalidation), depth-2
// prefetch (r11: spills -- (256,2) allocator caps VGPR at 128, observed
// 100/84/124/128 across all (256,2) builds). Neutral: pipelined epilogue
// (r9, kept: it also freed the ds_read off the critical path).
// ---------------------------------------------------------------------------

__global__ __launch_bounds__(256) void vq_prep(const float* __restrict__ w,
        float* __restrict__ wq2R, ushort* __restrict__ whiA,
        float* __restrict__ whPart, float* __restrict__ loss_slot) {
    __shared__ float sWH[16];
    const int t = threadIdx.x;
    const int tid = blockIdx.x * 256 + t;
    if (tid == 0) loss_slot[0] = 0.0f;   // d_out poisoned 0xAA each launch
    const int c = tid >> 4, hg = tid & 15, s = hg >> 1, khh = hg & 1;

    const float4* src = reinterpret_cast<const float4*>(w + (size_t)c * HH + (hg << 3));
    float4 a = src[0], b = src[1];
    _Float16 h0=(_Float16)a.x, h1=(_Float16)a.y, h2=(_Float16)a.z, h3=(_Float16)a.w;
    _Float16 h4=(_Float16)b.x, h5=(_Float16)b.y, h6=(_Float16)b.z, h7=(_Float16)b.w;
    half8 hi = {h0, h1, h2, h3, h4, h5, h6, h7};
    *reinterpret_cast<half8*>(&whiA[((size_t)(c >> 5) * 8 + s) * 512 +
                                    (((khh << 5) | (c & 31)) << 3)]) = hi;

    float ssq = 0.f;
    ssq = fmaf(a.x, a.x, ssq); ssq = fmaf(a.y, a.y, ssq);
    ssq = fmaf(a.z, a.z, ssq); ssq = fmaf(a.w, a.w, ssq);
    ssq = fmaf(b.x, b.x, ssq); ssq = fmaf(b.y, b.y, ssq);
    ssq = fmaf(b.z, b.z, ssq); ssq = fmaf(b.w, b.w, ssq);
    ssq += __shfl_xor(ssq, 1, 64);
    ssq += __shfl_xor(ssq, 2, 64);
    ssq += __shfl_xor(ssq, 4, 64);
    ssq += __shfl_xor(ssq, 8, 64);
    if (hg == 0) {
        int co = c & 31;
        wq2R[((c >> 5) << 5) + (((co >> 2) & 1) << 4) + ((co & 3) | ((co >> 3) << 2))]
            = 0.5f * ssq;
        sWH[t >> 4] = ssq;
    }
    __syncthreads();
    if (t == 0) {
        float mh = 0.f;
#pragma unroll
        for (int i = 0; i < 16; ++i) mh = fmaxf(mh, sWH[i]);
        whPart[blockIdx.x] = mh;
    }
}

// ---------------------------------------------------------------------------
// Fused scan (r3 base, 64 rows/block, 4 waves, grid 512) + SOFTWARE-PIPELINED
// epilogue: the min-tree/bound/collection of tile i-1 executes while tile i's
// MFMA chains are in flight (separate pipes, m114), and the wq2 C-term is
// added in the epilogue instead of C-initing the chain -- removing the
// serial ds_read + epilogue from the per-body critical path.
// ---------------------------------------------------------------------------
__global__ __launch_bounds__(256, 2) void vq_fused(
        const float* __restrict__ z, const float* __restrict__ w,
        const float* __restrict__ wq2R, const ushort* __restrict__ whiA,
        const float* __restrict__ whPart,
        float* __restrict__ out_zq, float* __restrict__ out_idx,
        float* __restrict__ out_loss) {
    __shared__ unsigned smin[64];
    __shared__ int rowcnt[64];
    __shared__ int rowovf[64];
    __shared__ int rowlist[64 * CAPR];
    __shared__ float swh[4];
    __shared__ int fb[64];
    __shared__ float lred[4];
    __shared__ __align__(16) float swq[KCODES];   // 16 KB wq2R copy

    const int t = threadIdx.x;
    const int lane = t & 63, wid = t >> 6;
    const int n = lane & 31, kh = lane >> 5;
    const int rowBase = blockIdx.x * 64;

    // codebook max ||w||^2 partial reduce (256 partials from prep)
    float wp = whPart[t];
#pragma unroll
    for (int off = 1; off < 64; off <<= 1) wp = fmaxf(wp, __shfl_xor(wp, off, 64));
    if (lane == 0) swh[wid] = wp;
    if (t < 64) { smin[t] = 0xFFFFFFFFu; rowcnt[t] = 0; rowovf[t] = 0; }

    // stage wq2R into LDS (epilogue wq2 reads become broadcast ds_reads)
    {
        const float4* g4 = reinterpret_cast<const float4*>(wq2R);
        float4* s4 = reinterpret_cast<float4*>(swq);
#pragma unroll
        for (int i = 0; i < 4; ++i) s4[i * 256 + t] = g4[i * 256 + t];
    }

    // ---- stage z: NEGATED hi fp16 B-frags for rows n and n+32 + norms ----
    half8 zbA[8], zbB[8];
    float zn2A = 0.f, zl2A = 0.f, zn2B = 0.f, zl2B = 0.f;
    {
        const float* zr = z + (size_t)(rowBase + n) * HH + (kh << 3);
#pragma unroll
        for (int s = 0; s < 8; ++s) {
            float4 a = *reinterpret_cast<const float4*>(zr + (s << 4));
            float4 b = *reinterpret_cast<const float4*>(zr + (s << 4) + 4);
            _Float16 h0=(_Float16)a.x, h1=(_Float16)a.y, h2=(_Float16)a.z, h3=(_Float16)a.w;
            _Float16 h4=(_Float16)b.x, h5=(_Float16)b.y, h6=(_Float16)b.z, h7=(_Float16)b.w;
            zbA[s] = (half8){-h0, -h1, -h2, -h3, -h4, -h5, -h6, -h7};
            zn2A = fmaf(a.x,a.x,zn2A); zn2A = fmaf(a.y,a.y,zn2A);
            zn2A = fmaf(a.z,a.z,zn2A); zn2A = fmaf(a.w,a.w,zn2A);
            zn2A = fmaf(b.x,b.x,zn2A); zn2A = fmaf(b.y,b.y,zn2A);
            zn2A = fmaf(b.z,b.z,zn2A); zn2A = fmaf(b.w,b.w,zn2A);
            float l0=a.x-(float)h0, l1=a.y-(float)h1, l2=a.z-(float)h2, l3=a.w-(float)h3;
            float l4=b.x-(float)h4, l5=b.y-(float)h5, l6=b.z-(float)h6, l7=b.w-(float)h7;
            zl2A = fmaf(l0,l0,zl2A); zl2A = fmaf(l1,l1,zl2A);
            zl2A = fmaf(l2,l2,zl2A); zl2A = fmaf(l3,l3,zl2A);
            zl2A = fmaf(l4,l4,zl2A); zl2A = fmaf(l5,l5,zl2A);
            zl2A = fmaf(l6,l6,zl2A); zl2A = fmaf(l7,l7,zl2A);
        }
        const float* zr2 = z + (size_t)(rowBase + 32 + n) * HH + (kh << 3);
#pragma unroll
        for (int s = 0; s < 8; ++s) {
            float4 a = *reinterpret_cast<const float4*>(zr2 + (s << 4));
            float4 b = *reinterpret_cast<const float4*>(zr2 + (s << 4) + 4);
            _Float16 h0=(_Float16)a.x, h1=(_Float16)a.y, h2=(_Float16)a.z, h3=(_Float16)a.w;
            _Float16 h4=(_Float16)b.x, h5=(_Float16)b.y, h6=(_Float16)b.z, h7=(_Float16)b.w;
            zbB[s] = (half8){-h0, -h1, -h2, -h3, -h4, -h5, -h6, -h7};
            zn2B = fmaf(a.x,a.x,zn2B); zn2B = fmaf(a.y,a.y,zn2B);
            zn2B = fmaf(a.z,a.z,zn2B); zn2B = fmaf(a.w,a.w,zn2B);
            zn2B = fmaf(b.x,b.x,zn2B); zn2B = fmaf(b.y,b.y,zn2B);
            zn2B = fmaf(b.z,b.z,zn2B); zn2B = fmaf(b.w,b.w,zn2B);
            float l0=a.x-(float)h0, l1=a.y-(float)h1, l2=a.z-(float)h2, l3=a.w-(float)h3;
            float l4=b.x-(float)h4, l5=b.y-(float)h5, l6=b.z-(float)h6, l7=b.w-(float)h7;
            zl2B = fmaf(l0,l0,zl2B); zl2B = fmaf(l1,l1,zl2B);
            zl2B = fmaf(l2,l2,zl2B); zl2B = fmaf(l3,l3,zl2B);
            zl2B = fmaf(l4,l4,zl2B); zl2B = fmaf(l5,l5,zl2B);
            zl2B = fmaf(l6,l6,zl2B); zl2B = fmaf(l7,l7,zl2B);
        }
        zn2A += __shfl_xor(zn2A, 32, 64);
        zl2A += __shfl_xor(zl2A, 32, 64);
        zn2B += __shfl_xor(zn2B, 32, 64);
        zl2B += __shfl_xor(zl2B, 32, 64);
    }
    __syncthreads();   // smin/cnt init + swh + swq visible

    // rigorous window: |d/2_true - est| <= E; accept if est < runmin + thrw,
    // thrw > 2E  =>  true argmin always collected; non-collected strictly
    // worse. (late wq2-add changes summation order by a few ulps -- covered
    // by the 1.01x / +4e-3 slack terms, and guarded by the exact re-eval.)
    float WH = sqrtf(fmaxf(fmaxf(swh[0], swh[1]), fmaxf(swh[2], swh[3])));
    float thrwA, thrwB;
    {
        float znr = sqrtf(zn2A), zlr = sqrtf(zl2A);
        float E = zlr * WH * 1.01f + (znr + zlr) * (WH * 4.8828125e-4f + 1e-6f) + 4e-3f;
        thrwA = 2.0f * E * 1.05f + 0.01f;
        float znr2 = sqrtf(zn2B), zlr2 = sqrtf(zl2B);
        float E2 = zlr2 * WH * 1.01f + (znr2 + zlr2) * (WH * 4.8828125e-4f + 1e-6f) + 4e-3f;
        thrwB = 2.0f * E2 * 1.05f + 0.01f;
    }

    const half8* A8 = reinterpret_cast<const half8*>(whiA);
    const int cb0 = wid << 5;
    float m1A = FLT_MAX, m1pA = FLT_MAX, m1B = FLT_MAX, m1pB = FLT_MAX;

    half8 afA[8], afB[8];
    {
        const half8* ap = A8 + ((size_t)cb0 << 3) * 64 + lane;
#pragma unroll
        for (int p = 0; p < 8; ++p) afA[p] = ap[p * 64];
    }

    const floatx16 zac = {0.f,0.f,0.f,0.f,0.f,0.f,0.f,0.f,
                          0.f,0.f,0.f,0.f,0.f,0.f,0.f,0.f};
    floatx16 pend0, pend1;   // pending accs (tile it-1), processed under tile it

    // epilogue for a PENDING tile: est = acc + wq2 (LDS, off critical path),
    // min-tree, bound check, rare reserve-then-store collection
    auto proc = [&](int pit, int pcb, const floatx16& wqp, const floatx16& acc,
                    float& m1, float& m1pub, float thrw, int row) {
        float est[16];
#pragma unroll
        for (int r = 0; r < 16; ++r) est[r] = acc[r] + wqp[r];
        float t00=fminf(est[0],est[1]),   t01=fminf(est[2],est[3]);
        float t02=fminf(est[4],est[5]),   t03=fminf(est[6],est[7]);
        float t04=fminf(est[8],est[9]),   t05=fminf(est[10],est[11]);
        float t06=fminf(est[12],est[13]), t07=fminf(est[14],est[15]);
        float tmin = fminf(fminf(fminf(t00,t01), fminf(t02,t03)),
                           fminf(fminf(t04,t05), fminf(t06,t07)));
        m1 = fminf(m1, tmin);
        if (m1 < m1pub) { atomicMin(&smin[row], fkey(m1)); m1pub = m1; }
        // register-only pre-check: shared bound <= local bound, so a local
        // fail proves no candidate here (m1 already includes this tile)
        if (pit > 0 && tmin < m1 + thrw) {
            float sh = funkey(((volatile unsigned*)smin)[row]);
            float bound = fminf(sh, m1) + thrw;
            if (tmin < bound) {
                unsigned cm = 0;
#pragma unroll
                for (int r = 0; r < 16; ++r)
                    if (est[r] < bound) cm |= (1u << r);
                int cc = __popc(cm);
                int ix = atomicAdd(&rowcnt[row], cc);
                if (ix + cc > CAPR) rowovf[row] = 1;
#pragma unroll
                for (int r = 0; r < 16; ++r) {
                    if (cm & (1u << r)) {
                        if (ix < CAPR)
                            rowlist[row * CAPR + ix] =
                                (pcb << 5) + (r & 3) + ((r >> 2) << 3) + (kh << 2);
                        ++ix;
                    }
                }
            }
        }
    };

    auto procPair = [&](int pit) {
        const int pcb = cb0 + ((pit < 32) ? pit : 0);
        const floatx16 wqp =
            *reinterpret_cast<const floatx16*>(&swq[(pcb << 5) + (kh << 4)]);
        proc(pit, pcb, wqp, pend0, m1A, m1pA, thrwA, n);
        proc(pit, pcb, wqp, pend1, m1B, m1pB, thrwB, n + 32);
    };

    auto body = [&](int it, half8 (&cur)[8], half8 (&nxt)[8]) {
        if (it < 32) {
            const int cbn = cb0 + ((it + 1) & 31);
            const half8* ap = A8 + ((size_t)cbn << 3) * 64 + lane;
#pragma unroll
            for (int p = 0; p < 8; ++p) nxt[p] = ap[p * 64];
        }
        // zero-C chains: no ds_read on the critical path; wq2 added in proc
        floatx16 a0 = __builtin_amdgcn_mfma_f32_32x32x16_f16(cur[0], zbA[0], zac, 0, 0, 0);
        floatx16 a1 = __builtin_amdgcn_mfma_f32_32x32x16_f16(cur[0], zbB[0], zac, 0, 0, 0);
#pragma unroll
        for (int s = 1; s < 8; ++s) {
            a0 = __builtin_amdgcn_mfma_f32_32x32x16_f16(cur[s], zbA[s], a0, 0, 0, 0);
            a1 = __builtin_amdgcn_mfma_f32_32x32x16_f16(cur[s], zbB[s], a1, 0, 0, 0);
        }
        // process PREVIOUS tile's accs while this tile's MFMAs are in flight
        if (it > 0) procPair(it - 1);
        pend0 = a0; pend1 = a1;
    };

#pragma unroll 1
    for (int itp = 0; itp < 16; ++itp) {
        body(2 * itp,     afA, afB);
        body(2 * itp + 1, afB, afA);
    }
    body(32, afA, afB);   // re-pass tile 0 (warm bound)
    procPair(32);         // drain the last pending (tile 0, collect=true)
    __syncthreads();

    // ---- exact fp32 eval of candidates (4 threads per row, 64 rows) ----
    {
        const int erow = t >> 2, eq = t & 3;
        int cnt = rowcnt[erow];
        bool ovf = (rowovf[erow] != 0) || (cnt > CAPR) || (cnt == 0);
        if (cnt > CAPR) cnt = CAPR;
        if (ovf) {
            if (eq == 0) rowovf[erow] = 1;
        } else {
            const float* zs = z + (size_t)(rowBase + erow) * HH + (eq << 5);
            float4 z0 = *reinterpret_cast<const float4*>(zs);
            float4 z1 = *reinterpret_cast<const float4*>(zs + 4);
            float4 z2 = *reinterpret_cast<const float4*>(zs + 8);
            float4 z3 = *reinterpret_cast<const float4*>(zs + 12);
            float4 z4v = *reinterpret_cast<const float4*>(zs + 16);
            float4 z5 = *reinterpret_cast<const float4*>(zs + 20);
            float4 z6 = *reinterpret_cast<const float4*>(zs + 24);
            float4 z7 = *reinterpret_cast<const float4*>(zs + 28);
            float bd = FLT_MAX; int bc = 0x7fffffff;
            for (int j = 0; j < cnt; ++j) {
                int c = rowlist[erow * CAPR + j];
                const float* wr = w + (size_t)c * HH + (eq << 5);
                float4 w0 = *reinterpret_cast<const float4*>(wr);
                float4 w1 = *reinterpret_cast<const float4*>(wr + 4);
                float4 w2 = *reinterpret_cast<const float4*>(wr + 8);
                float4 w3 = *reinterpret_cast<const float4*>(wr + 12);
                float4 w4 = *reinterpret_cast<const float4*>(wr + 16);
                float4 w5 = *reinterpret_cast<const float4*>(wr + 20);
                float4 w6 = *reinterpret_cast<const float4*>(wr + 24);
                float4 w7 = *reinterpret_cast<const float4*>(wr + 28);
                float dot = 0.f;
                dot = fmaf(z0.x,w0.x,dot); dot = fmaf(z0.y,w0.y,dot);
                dot = fmaf(z0.z,w0.z,dot); dot = fmaf(z0.w,w0.w,dot);
                dot = fmaf(z1.x,w1.x,dot); dot = fmaf(z1.y,w1.y,dot);
                dot = fmaf(z1.z,w1.z,dot); dot = fmaf(z1.w,w1.w,dot);
                dot = fmaf(z2.x,w2.x,dot); dot = fmaf(z2.y,w2.y,dot);
                dot = fmaf(z2.z,w2.z,dot); dot = fmaf(z2.w,w2.w,dot);
                dot = fmaf(z3.x,w3.x,dot); dot = fmaf(z3.y,w3.y,dot);
                dot = fmaf(z3.z,w3.z,dot); dot = fmaf(z3.w,w3.w,dot);
                dot = fmaf(z4v.x,w4.x,dot); dot = fmaf(z4v.y,w4.y,dot);
                dot = fmaf(z4v.z,w4.z,dot); dot = fmaf(z4v.w,w4.w,dot);
                dot = fmaf(z5.x,w5.x,dot); dot = fmaf(z5.y,w5.y,dot);
                dot = fmaf(z5.z,w5.z,dot); dot = fmaf(z5.w,w5.w,dot);
                dot = fmaf(z6.x,w6.x,dot); dot = fmaf(z6.y,w6.y,dot);
                dot = fmaf(z6.z,w6.z,dot); dot = fmaf(z6.w,w6.w,dot);
                dot = fmaf(z7.x,w7.x,dot); dot = fmaf(z7.y,w7.y,dot);
                dot = fmaf(z7.z,w7.z,dot); dot = fmaf(z7.w,w7.w,dot);
                dot += __shfl_xor(dot, 1, 64);
                dot += __shfl_xor(dot, 2, 64);
                int co = c & 31;
                float wq2v = swq[((c >> 5) << 5) + (((co >> 2) & 1) << 4)
                                 + ((co & 3) | ((co >> 3) << 2))];
                float d2 = wq2v - dot;
                if (d2 < bd || (d2 == bd && c < bc)) { bd = d2; bc = c; }
            }
            if (eq == 0) { fb[erow] = bc; out_idx[rowBase + erow] = (float)bc; }
        }
    }
    __syncthreads();

    // ---- rigorous fallback: full exact scan for overflow rows (~never),
    // rows distributed across the 4 waves ----
    for (int rr = wid; rr < 64; rr += 4) {
        if (rowovf[rr] == 0) continue;
        const float* zrow = z + (size_t)(rowBase + rr) * HH;
        float bd = FLT_MAX; int bc = 0x7fffffff;
        for (int kq = 0; kq < 64; ++kq) {
            int c = (kq << 6) + lane;
            const float* wr = w + (size_t)c * HH;
            float dot = 0.f;
            for (int h4 = 0; h4 < 32; ++h4) {
                float4 wv = *reinterpret_cast<const float4*>(wr + (h4 << 2));
                float4 zv = *reinterpret_cast<const float4*>(zrow + (h4 << 2));
                dot = fmaf(zv.x,wv.x,dot); dot = fmaf(zv.y,wv.y,dot);
                dot = fmaf(zv.z,wv.z,dot); dot = fmaf(zv.w,wv.w,dot);
            }
            int co = c & 31;
            float wq2v = swq[((c >> 5) << 5) + (((co >> 2) & 1) << 4)
                             + ((co & 3) | ((co >> 3) << 2))];
            float d2 = wq2v - dot;
            if (d2 < bd || (d2 == bd && c < bc)) { bd = d2; bc = c; }
        }
#pragma unroll
        for (int off = 1; off < 64; off <<= 1) {
            float od = __shfl_xor(bd, off, 64);
            int oc = __shfl_xor(bc, off, 64);
            if (od < bd || (od == bd && oc < bc)) { bd = od; bc = oc; }
        }
        if (lane == 0) { fb[rr] = bc; out_idx[rowBase + rr] = (float)bc; }
    }
    __syncthreads();

    // ---- zq gather + loss (proven epilogue) ----
    const float4* z4 = reinterpret_cast<const float4*>(z);
    float lsum = 0.f;
#pragma unroll
    for (int i = 0; i < 8; ++i) {
        int g = i * 256 + t;
        int r = g >> 5, f4 = g & 31;
        int code = fb[r];
        float4 wv = *reinterpret_cast<const float4*>(w + (size_t)code * HH + (f4 << 2));
        float4 zv = z4[(size_t)(rowBase + r) * 32 + f4];
        float dx = wv.x - zv.x, dy = wv.y - zv.y, dz = wv.z - zv.z, dw = wv.w - zv.w;
        lsum = fmaf(dx, dx, lsum); lsum = fmaf(dy, dy, lsum);
        lsum = fmaf(dz, dz, lsum); lsum = fmaf(dw, dw, lsum);
        *reinterpret_cast<float4*>(out_zq + (size_t)(rowBase + r) * HH + (f4 << 2)) = wv;
    }
#pragma unroll
    for (int off = 1; off < 64; off <<= 1) lsum += __shfl_xor(lsum, off, 64);
    if (lane == 0) lred[wid] = lsum;
    __syncthreads();
    if (t == 0) {
        float total = lred[0] + lred[1] + lred[2] + lred[3];
        atomicAdd(out_loss, total * (1.25f / 4194304.0f));  // (0.25+1)*mean, N*H
    }
}

// ---------------- fallback path (Round-2 kernels, proven) -------------------
__device__ __forceinline__ int plane_off_fb(int r, int hu) {
    return ((hu << 6) | (r ^ (hu & 7))) << 3;
}

__global__ __launch_bounds__(256) void vq_prep_fb(const float* __restrict__ w,
                                                  float* __restrict__ wsq,
                                                  float* __restrict__ loss_slot) {
    int c = blockIdx.x * 256 + threadIdx.x;
    if (c == 0) loss_slot[0] = 0.0f;
    if (c < KCODES) {
        const float4* row = reinterpret_cast<const float4*>(w + (size_t)c * HH);
        float s = 0.0f;
#pragma unroll
        for (int i = 0; i < HH / 4; ++i) {
            float4 v = row[i];
            s = fmaf(v.x, v.x, s); s = fmaf(v.y, v.y, s);
            s = fmaf(v.z, v.z, s); s = fmaf(v.w, v.w, s);
        }
        wsq[c] = s;
    }
}

__device__ __forceinline__ void stage_tile_fb(const float4* __restrict__ src4,
                                              ushort* lds, int hi_base, int lo_base,
                                              int t) {
#pragma unroll
    for (int p = 0; p < 8; ++p) {
        int g = p * 256 + t;
        int r = g >> 5, f4 = g & 31;
        float4 v = src4[g];
        _Float16 h0 = (_Float16)v.x, h1 = (_Float16)v.y,
                 h2 = (_Float16)v.z, h3 = (_Float16)v.w;
        half4_t hv = {h0, h1, h2, h3};
        half4_t lv = {(_Float16)(v.x - (float)h0), (_Float16)(v.y - (float)h1),
                      (_Float16)(v.z - (float)h2), (_Float16)(v.w - (float)h3)};
        int off = plane_off_fb(r, f4 >> 1) + ((f4 & 1) << 2);
        *reinterpret_cast<half4_t*>(&lds[hi_base + off]) = hv;
        *reinterpret_cast<half4_t*>(&lds[lo_base + off]) = lv;
    }
}

__global__ __launch_bounds__(256, 2) void vq_main_fb(const float* __restrict__ z,
                                                     const float* __restrict__ w,
                                                     const float* __restrict__ wsq,
                                                     float* __restrict__ out_zq,
                                                     float* __restrict__ out_idx,
                                                     float* __restrict__ out_loss) {
    __shared__ __align__(16) ushort lds[32768];
    const int t = threadIdx.x, lane = t & 63, wid = t >> 6;
    const int q = lane >> 4, m15 = lane & 15;
    const int wrow = (wid >> 1) << 5, wcol = (wid & 1) << 5;
    const int rowBase = blockIdx.x * 64;

    stage_tile_fb(reinterpret_cast<const float4*>(z + (size_t)rowBase * HH), lds, 0, 8192, t);

    float best[2][4]; int bidx[2][4];
#pragma unroll
    for (int mt = 0; mt < 2; ++mt)
#pragma unroll
        for (int rg = 0; rg < 4; ++rg) { best[mt][rg] = FLT_MAX; bidx[mt][rg] = 0; }

    const int ar0 = wrow + m15, bn0 = wcol + m15;

    for (int k0 = 0; k0 < KCODES; k0 += 64) {
        __syncthreads();
        stage_tile_fb(reinterpret_cast<const float4*>(w + (size_t)k0 * HH), lds, 16384, 24576, t);
        __syncthreads();
        floatx4 acc[2][2];
#pragma unroll
        for (int mt = 0; mt < 2; ++mt)
#pragma unroll
            for (int nt = 0; nt < 2; ++nt) acc[mt][nt] = (floatx4){0.f, 0.f, 0.f, 0.f};
#pragma unroll
        for (int c = 0; c < 4; ++c) {
            const int hu = (c << 2) + q;
            half8 zh0 = *reinterpret_cast<half8*>(&lds[plane_off_fb(ar0, hu)]);
            half8 zh1 = *reinterpret_cast<half8*>(&lds[plane_off_fb(ar0 + 16, hu)]);
            half8 zl0 = *reinterpret_cast<half8*>(&lds[8192 + plane_off_fb(ar0, hu)]);
            half8 zl1 = *reinterpret_cast<half8*>(&lds[8192 + plane_off_fb(ar0 + 16, hu)]);
            half8 wh0 = *reinterpret_cast<half8*>(&lds[16384 + plane_off_fb(bn0, hu)]);
            half8 wh1 = *reinterpret_cast<half8*>(&lds[16384 + plane_off_fb(bn0 + 16, hu)]);
            half8 wl0 = *reinterpret_cast<half8*>(&lds[24576 + plane_off_fb(bn0, hu)]);
            half8 wl1 = *reinterpret_cast<half8*>(&lds[24576 + plane_off_fb(bn0 + 16, hu)]);
            acc[0][0] = __builtin_amdgcn_mfma_f32_16x16x32_f16(zh0, wh0, acc[0][0], 0, 0, 0);
            acc[0][1] = __builtin_amdgcn_mfma_f32_16x16x32_f16(zh0, wh1, acc[0][1], 0, 0, 0);
            acc[1][0] = __builtin_amdgcn_mfma_f32_16x16x32_f16(zh1, wh0, acc[1][0], 0, 0, 0);
            acc[1][1] = __builtin_amdgcn_mfma_f32_16x16x32_f16(zh1, wh1, acc[1][1], 0, 0, 0);
            acc[0][0] = __builtin_amdgcn_mfma_f32_16x16x32_f16(zh0, wl0, acc[0][0], 0, 0, 0);
            acc[0][1] = __builtin_amdgcn_mfma_f32_16x16x32_f16(zh0, wl1, acc[0][1], 0, 0, 0);
            acc[1][0] = __builtin_amdgcn_mfma_f32_16x16x32_f16(zh1, wl0, acc[1][0], 0, 0, 0);
            acc[1][1] = __builtin_amdgcn_mfma_f32_16x16x32_f16(zh1, wl1, acc[1][1], 0, 0, 0);
            acc[0][0] = __builtin_amdgcn_mfma_f32_16x16x32_f16(zl0, wh0, acc[0][0], 0, 0, 0);
            acc[0][1] = __builtin_amdgcn_mfma_f32_16x16x32_f16(zl0, wh1, acc[0][1], 0, 0, 0);
            acc[1][0] = __builtin_amdgcn_mfma_f32_16x16x32_f16(zl1, wh0, acc[1][0], 0, 0, 0);
            acc[1][1] = __builtin_amdgcn_mfma_f32_16x16x32_f16(zl1, wh1, acc[1][1], 0, 0, 0);
        }
        float wq0 = wsq[k0 + bn0], wq1 = wsq[k0 + bn0 + 16];
#pragma unroll
        for (int mt = 0; mt < 2; ++mt)
#pragma unroll
            for (int nt = 0; nt < 2; ++nt) {
                int code = k0 + wcol + (nt << 4) + m15;
                float wqv = nt ? wq1 : wq0;
#pragma unroll
                for (int rg = 0; rg < 4; ++rg) {
                    float s = fmaf(-2.0f, acc[mt][nt][rg], wqv);
                    if (s < best[mt][rg]) { best[mt][rg] = s; bidx[mt][rg] = code; }
                }
            }
    }
#pragma unroll
    for (int off = 1; off < 16; off <<= 1)
#pragma unroll
        for (int mt = 0; mt < 2; ++mt)
#pragma unroll
            for (int rg = 0; rg < 4; ++rg) {
                float os = __shfl_xor(best[mt][rg], off, 64);
                int   oi = __shfl_xor(bidx[mt][rg], off, 64);
                if (os < best[mt][rg] || (os == best[mt][rg] && oi < bidx[mt][rg])) {
                    best[mt][rg] = os; bidx[mt][rg] = oi;
                }
            }
    float* epmin = reinterpret_cast<float*>(lds);
    int*   epidx = reinterpret_cast<int*>(reinterpret_cast<char*>(lds) + 512);
    int*   fbidx = reinterpret_cast<int*>(reinterpret_cast<char*>(lds) + 1024);
    float* lredf = reinterpret_cast<float*>(reinterpret_cast<char*>(lds) + 1280);
    __syncthreads();
    if (m15 == 0) {
        int g = wid & 1;
#pragma unroll
        for (int mt = 0; mt < 2; ++mt)
#pragma unroll
            for (int rg = 0; rg < 4; ++rg) {
                int row = wrow + (mt << 4) + (q << 2) + rg;
                epmin[g * 64 + row] = best[mt][rg];
                epidx[g * 64 + row] = bidx[mt][rg];
            }
    }
    __syncthreads();
    if (t < 64) {
        float s0 = epmin[t], s1 = epmin[64 + t];
        int   i0 = epidx[t], i1 = epidx[64 + t];
        int   fi = (s1 < s0 || (s1 == s0 && i1 < i0)) ? i1 : i0;
        fbidx[t] = fi;
        out_idx[rowBase + t] = (float)fi;
    }
    __syncthreads();
    const float4* z4 = reinterpret_cast<const float4*>(z);
    float lsum = 0.0f;
#pragma unroll
    for (int i = 0; i < 8; ++i) {
        int g = i * 256 + t;
        int r = g >> 5, f4 = g & 31;
        int code = fbidx[r];
        float4 wv = *reinterpret_cast<const float4*>(w + (size_t)code * HH + (f4 << 2));
        float4 zv = z4[(size_t)(rowBase + r) * 32 + f4];
        float dx = wv.x - zv.x, dy = wv.y - zv.y, dz = wv.z - zv.z, dw = wv.w - zv.w;
        lsum = fmaf(dx, dx, lsum); lsum = fmaf(dy, dy, lsum);
        lsum = fmaf(dz, dz, lsum); lsum = fmaf(dw, dw, lsum);
        *reinterpret_cast<float4*>(out_zq + (size_t)(rowBase + r) * HH + (f4 << 2)) = wv;
    }
#pragma unroll
    for (int off = 1; off < 64; off <<= 1) lsum += __shfl_xor(lsum, off, 64);
    if (lane == 0) lredf[wid] = lsum;
    __syncthreads();
    if (t == 0)
        atomicAdd(out_loss, (lredf[0] + lredf[1] + lredf[2] + lredf[3]) * (1.25f / 4194304.0f));
}

extern "C" void kernel_launch(void* const* d_in, const int* in_sizes, int n_in,
                              void* d_out, int out_size, void* d_ws, size_t ws_size,
                              hipStream_t stream) {
    (void)in_sizes; (void)n_in; (void)out_size;
    const float* z = (const float*)d_in[0];
    const float* w = (const float*)d_in[1];
    float* out      = (float*)d_out;
    float* out_zq   = out;
    float* out_idx  = out + (size_t)NROWS * HH;
    float* out_loss = out_idx + NROWS;

    char* wsb = (char*)d_ws;
    float*  wq2R   = (float*)(wsb + 0);        // 16 KB
    float*  whPart = (float*)(wsb + 16384);    // 1 KB
    ushort* whiA   = (ushort*)(wsb + 17408);   // 1 MB f16 codes, A-frag order
    const size_t WS_NEED = 17408 + (size_t)KCODES * HH * 2;

    if (ws_size >= WS_NEED) {
        vq_prep<<<256, 256, 0, stream>>>(w, wq2R, whiA, whPart, out_loss);
        vq_fused<<<NROWS / 64, 256, 0, stream>>>(z, w, wq2R, whiA, whPart,
                                                 out_zq, out_idx, out_loss);
    } else {
        float* wsq = (float*)d_ws;
        vq_prep_fb<<<KCODES / 256, 256, 0, stream>>>(w, wsq, out_loss);
        vq_main_fb<<<NROWS / 64, 256, 0, stream>>>(z, w, wsq, out_zq, out_idx, out_loss);
    }
}